// Round 1
// baseline (856.095 us; speedup 1.0000x reference)
//
#include <hip/hip_runtime.h>
#include <math.h>

#define N_NODES 65536
#define NPG     512
#define NGRAPH  128
#define E_EDGES 524288
#define MAXDEG  64
#define NHEADS  8
#define F1      20
#define HID     128
#define D160    160
#define KSEL    256

__device__ __forceinline__ float lrelu(float x){ return x > 0.f ? x : 0.2f*x; }

// ---------------- ELL adjacency build (dst -> list of src) ----------------
__global__ void k_build_ell(const int* __restrict__ src, const int* __restrict__ dst,
                            int* __restrict__ deg, int* __restrict__ ell){
    int e = blockIdx.x*blockDim.x + threadIdx.x;
    if(e >= E_EDGES) return;
    int d = dst[e];
    int p = atomicAdd(&deg[d], 1);
    if(p < MAXDEG) ell[d*MAXDEG + p] = src[e];
}

// ---------------- conv A1: z from one-hot gather + es/ed dots ----------------
__global__ void k_a1_z(const int* __restrict__ x, const float* __restrict__ W,
                       const float* __restrict__ asrc, const float* __restrict__ adst,
                       float* __restrict__ z8, float* __restrict__ es8, float* __restrict__ ed8){
    int t = blockIdx.x*blockDim.x + threadIdx.x;
    if(t >= N_NODES*NHEADS) return;
    int n = t >> 3, h = t & 7;
    int lbl = x[n];
    const float* wrow = W + lbl*D160 + h*F1;
    const float* as = asrc + h*F1;
    const float* ad = adst + h*F1;
    float* zr = z8 + n*D160 + h*F1;
    float es = 0.f, ed = 0.f;
    #pragma unroll
    for(int f=0; f<F1; ++f){
        float v = wrow[f];
        zr[f] = v;
        es += v*as[f];
        ed += v*ad[f];
    }
    es8[t] = es; ed8[t] = ed;
}

// ---------------- es/ed dots for 8-head conv given z ----------------
__global__ void k_esed8(const float* __restrict__ z8, const float* __restrict__ asrc,
                        const float* __restrict__ adst,
                        float* __restrict__ es8, float* __restrict__ ed8){
    int t = blockIdx.x*blockDim.x + threadIdx.x;
    if(t >= N_NODES*NHEADS) return;
    int n = t >> 3, h = t & 7;
    const float* zr = z8 + n*D160 + h*F1;
    const float* as = asrc + h*F1;
    const float* ad = adst + h*F1;
    float es = 0.f, ed = 0.f;
    #pragma unroll
    for(int f=0; f<F1; ++f){
        float v = zr[f];
        es += v*as[f];
        ed += v*ad[f];
    }
    es8[t] = es; ed8[t] = ed;
}

// ---------------- 8-head attention aggregate (thread per node,head) ----------------
__global__ void k_attn8(const int* __restrict__ deg, const int* __restrict__ ell,
                        const float* __restrict__ z8, const float* __restrict__ es8,
                        const float* __restrict__ ed8, const float* __restrict__ bias,
                        float* __restrict__ out){
    int t = blockIdx.x*blockDim.x + threadIdx.x;
    if(t >= N_NODES*NHEADS) return;
    int n = t >> 3, h = t & 7;
    int dg = deg[n]; if(dg > MAXDEG) dg = MAXDEG;
    float edn = ed8[t];
    float eself = lrelu(es8[t] + edn);
    const int* el = ell + n*MAXDEG;
    float m = eself;
    for(int i=0;i<dg;++i){
        int s = el[i];
        float e = lrelu(es8[s*NHEADS + h] + edn);
        m = fmaxf(m, e);
    }
    float w = expf(eself - m);
    float den = w;
    float acc[F1];
    const float* zn = z8 + n*D160 + h*F1;
    #pragma unroll
    for(int f=0; f<F1; ++f) acc[f] = w*zn[f];
    for(int i=0;i<dg;++i){
        int s = el[i];
        float e = lrelu(es8[s*NHEADS + h] + edn);
        float wi = expf(e - m);
        den += wi;
        const float* zs = z8 + s*D160 + h*F1;
        #pragma unroll
        for(int f=0; f<F1; ++f) acc[f] += wi*zs[f];
    }
    float inv = 1.f/(den + 1e-16f);
    float* o = out + n*D160 + h*F1;
    const float* bb = bias + h*F1;
    #pragma unroll
    for(int f=0; f<F1; ++f) o[f] = fmaxf(acc[f]*inv + bb[f], 0.f);
}

// ---------------- fp32 GEMM: C[N,OUT] = A[N,IN] @ W[IN,OUT], W in LDS ----------------
template<int IN, int OUT, int ROWS>
__global__ void k_gemm(const float* __restrict__ A, const float* __restrict__ W,
                       float* __restrict__ C){
    extern __shared__ float Wl[];
    const int GROUPS = OUT/8;
    const int NTH = GROUPS*(ROWS/2);
    int tid = threadIdx.y*GROUPS + threadIdx.x;
    for(int i=tid; i<IN*OUT; i+=NTH) Wl[i] = W[i];
    __syncthreads();
    int r0 = blockIdx.x*ROWS + threadIdx.y*2;
    int r1 = r0 + 1;
    int c  = threadIdx.x*8;
    float acc[16];
    #pragma unroll
    for(int j=0;j<16;++j) acc[j]=0.f;
    const float* Ar0 = A + (size_t)r0*IN;
    const float* Ar1 = A + (size_t)r1*IN;
    for(int k=0; k<IN; k+=4){
        float4 a0 = *reinterpret_cast<const float4*>(Ar0+k);
        float4 a1 = *reinterpret_cast<const float4*>(Ar1+k);
        #pragma unroll
        for(int kk=0; kk<4; ++kk){
            const float* wr = Wl + (k+kk)*OUT + c;
            float av0 = (&a0.x)[kk];
            float av1 = (&a1.x)[kk];
            #pragma unroll
            for(int j=0;j<8;++j){
                float wv = wr[j];
                acc[j]   += av0*wv;
                acc[8+j] += av1*wv;
            }
        }
    }
    float* C0 = C + (size_t)r0*OUT + c;
    float* C1 = C + (size_t)r1*OUT + c;
    #pragma unroll
    for(int j=0;j<8;++j) C0[j] = acc[j];
    #pragma unroll
    for(int j=0;j<8;++j) C1[j] = acc[8+j];
}

// ---------------- two dots per node over HID dims (wave per node) ----------------
__global__ void k_dot2(const float* __restrict__ Z, const float* __restrict__ va,
                       const float* __restrict__ vb, float* __restrict__ oa,
                       float* __restrict__ ob){
    int gt = blockIdx.x*blockDim.x + threadIdx.x;
    int n = gt >> 6;
    int l = threadIdx.x & 63;
    if(n >= N_NODES) return;
    const float* z = Z + (size_t)n*HID;
    float pa = z[l]*va[l] + z[l+64]*va[l+64];
    float pb = z[l]*vb[l] + z[l+64]*vb[l+64];
    for(int o=32;o>0;o>>=1){ pa += __shfl_xor(pa,o); pb += __shfl_xor(pb,o); }
    if(l==0){ oa[n]=pa; ob[n]=pb; }
}

// ---------------- 1-head attention aggregate (wave per node) ----------------
__global__ void k_attn1(const int* __restrict__ deg, const int* __restrict__ ell,
                        const float* __restrict__ Z, const float* __restrict__ es,
                        const float* __restrict__ ed, const float* __restrict__ bias,
                        float* __restrict__ out){
    int gt = blockIdx.x*blockDim.x + threadIdx.x;
    int n = gt >> 6;
    int l = threadIdx.x & 63;
    if(n >= N_NODES) return;
    int dg = deg[n]; if(dg > MAXDEG) dg = MAXDEG;
    float edn = ed[n];
    float eself = lrelu(es[n] + edn);
    int s_l = 0; float e_l = -1e30f;
    if(l < dg){ s_l = ell[n*MAXDEG + l]; e_l = lrelu(es[s_l] + edn); }
    float m = fmaxf(e_l, eself);
    for(int o=32;o>0;o>>=1) m = fmaxf(m, __shfl_xor(m,o));
    float w_l = (l < dg) ? expf(e_l - m) : 0.f;
    float den = w_l;
    for(int o=32;o>0;o>>=1) den += __shfl_xor(den,o);
    float wself = expf(eself - m);
    den += wself;
    float acc0 = wself*Z[(size_t)n*HID + l];
    float acc1 = wself*Z[(size_t)n*HID + 64 + l];
    for(int i=0;i<dg;++i){
        int s = __shfl(s_l, i);
        float w = __shfl(w_l, i);
        acc0 += w*Z[(size_t)s*HID + l];
        acc1 += w*Z[(size_t)s*HID + 64 + l];
    }
    float inv = 1.f/(den + 1e-16f);
    out[(size_t)n*HID + l]      = fmaxf(acc0*inv + bias[l],      0.f);
    out[(size_t)n*HID + 64 + l] = fmaxf(acc1*inv + bias[64 + l], 0.f);
}

// ---------------- pooling score: tanh(sum_nbr y[s] + r[n] + b) ----------------
__global__ void k_score(const int* __restrict__ deg, const int* __restrict__ ell,
                        const float* __restrict__ yrel, const float* __restrict__ rroot,
                        const float* __restrict__ bpool, float* __restrict__ score){
    int n = blockIdx.x*blockDim.x + threadIdx.x;
    if(n >= N_NODES) return;
    int dg = deg[n]; if(dg > MAXDEG) dg = MAXDEG;
    float s = rroot[n] + bpool[0];
    const int* el = ell + n*MAXDEG;
    for(int i=0;i<dg;++i) s += yrel[el[i]];
    score[n] = tanhf(s);
}

// ---------------- per-graph top-k (bitonic, desc by score, tie asc idx) + pooled max ----------------
__global__ void k_topk_pool(const float* __restrict__ score, const float* __restrict__ H,
                            float* __restrict__ pooled, float* __restrict__ perm_f,
                            float* __restrict__ sv, float* __restrict__ batch_f){
    __shared__ float skey[NPG];
    __shared__ int   sidx[NPG];
    int g = blockIdx.x;
    int t = threadIdx.x;
    int base = g*NPG;
    skey[t] = score[base + t];
    sidx[t] = t;
    __syncthreads();
    for(int k=2; k<=NPG; k<<=1){
        for(int j=k>>1; j>0; j>>=1){
            int ixj = t ^ j;
            if(ixj > t){
                float ka = skey[t], kb = skey[ixj];
                int   ia = sidx[t], ib = sidx[ixj];
                bool up = ((t & k) == 0);
                bool t_after = (ka < kb) || (ka == kb && ia > ib);
                if(t_after == up){
                    skey[t] = kb; skey[ixj] = ka;
                    sidx[t] = ib; sidx[ixj] = ia;
                }
            }
            __syncthreads();
        }
    }
    if(t < KSEL){
        perm_f[g*KSEL + t]  = (float)(base + sidx[t]);
        sv[g*KSEL + t]      = skey[t];
        batch_f[g*KSEL + t] = (float)g;
    }
    __syncthreads();
    if(t < HID){
        float mx = -1e30f;
        for(int kk=0; kk<KSEL; ++kk){
            float v = H[(size_t)(base + sidx[kk])*HID + t] * skey[kk];
            mx = fmaxf(mx, v);
        }
        pooled[g*HID + t] = mx;
    }
}

extern "C" void kernel_launch(void* const* d_in, const int* in_sizes, int n_in,
                              void* d_out, int out_size, void* d_ws, size_t ws_size,
                              hipStream_t stream) {
    const int*   x       = (const int*)  d_in[0];
    const int*   eidx    = (const int*)  d_in[1];
    const float* W_a1    = (const float*)d_in[3];
    const float* asrc_a1 = (const float*)d_in[4];
    const float* adst_a1 = (const float*)d_in[5];
    const float* b_a1    = (const float*)d_in[6];
    const float* W_a2    = (const float*)d_in[7];
    const float* asrc_a2 = (const float*)d_in[8];
    const float* adst_a2 = (const float*)d_in[9];
    const float* b_a2    = (const float*)d_in[10];
    const float* W_b1    = (const float*)d_in[11];
    const float* asrc_b1 = (const float*)d_in[12];
    const float* adst_b1 = (const float*)d_in[13];
    const float* b_b1    = (const float*)d_in[14];
    const float* W_b2    = (const float*)d_in[15];
    const float* asrc_b2 = (const float*)d_in[16];
    const float* adst_b2 = (const float*)d_in[17];
    const float* b_b2    = (const float*)d_in[18];
    const float* w_rel   = (const float*)d_in[19];
    const float* w_root  = (const float*)d_in[20];
    const float* b_pool  = (const float*)d_in[21];

    const int* e_src = eidx;
    const int* e_dst = eidx + E_EDGES;

    char* ws = (char*)d_ws;
    size_t off = 0;
    auto alloc = [&](size_t bytes)->char*{
        char* p = ws + off;
        off += (bytes + 255) & ~(size_t)255;
        return p;
    };
    int*   deg   = (int*)  alloc((size_t)N_NODES*4);
    int*   ell   = (int*)  alloc((size_t)N_NODES*MAXDEG*4);
    float* z8    = (float*)alloc((size_t)N_NODES*D160*4);
    float* h8    = (float*)alloc((size_t)N_NODES*D160*4);
    float* zc    = (float*)alloc((size_t)N_NODES*HID*4);
    float* hc    = (float*)alloc((size_t)N_NODES*HID*4);
    float* es8   = (float*)alloc((size_t)N_NODES*NHEADS*4);
    float* ed8   = (float*)alloc((size_t)N_NODES*NHEADS*4);
    float* es1   = (float*)alloc((size_t)N_NODES*4);
    float* ed1   = (float*)alloc((size_t)N_NODES*4);
    float* yrel  = (float*)alloc((size_t)N_NODES*4);
    float* rroot = (float*)alloc((size_t)N_NODES*4);
    float* score = (float*)alloc((size_t)N_NODES*4);
    (void)ws_size; (void)n_in; (void)in_sizes; (void)out_size;

    float* out      = (float*)d_out;
    float* pooled   = out;                        // 128*128
    float* perm_f   = out + NGRAPH*HID;           // 32768
    float* sv       = perm_f + NGRAPH*KSEL;       // 32768
    float* batch_f  = sv + NGRAPH*KSEL;           // 32768

    hipMemsetAsync(deg, 0, (size_t)N_NODES*4, stream);
    k_build_ell<<<E_EDGES/256, 256, 0, stream>>>(e_src, e_dst, deg, ell);

    // ---- GATNet A, conv1 (D=100 -> 20x8) ----
    k_a1_z<<<N_NODES*NHEADS/256, 256, 0, stream>>>(x, W_a1, asrc_a1, adst_a1, z8, es8, ed8);
    k_attn8<<<N_NODES*NHEADS/256, 256, 0, stream>>>(deg, ell, z8, es8, ed8, b_a1, h8);

    // ---- GATNet A, conv2 (160 -> 128) ----
    k_gemm<D160, HID, 128><<<N_NODES/128, dim3(16,64), D160*HID*4, stream>>>(h8, W_a2, zc);
    k_dot2<<<N_NODES/4, 256, 0, stream>>>(zc, asrc_a2, adst_a2, es1, ed1);
    k_attn1<<<N_NODES/4, 256, 0, stream>>>(deg, ell, zc, es1, ed1, b_a2, hc);

    // ---- GATNet B, conv1 (128 -> 20x8) ----
    k_gemm<HID, D160, 64><<<N_NODES/64, dim3(20,32), HID*D160*4, stream>>>(hc, W_b1, z8);
    k_esed8<<<N_NODES*NHEADS/256, 256, 0, stream>>>(z8, asrc_b1, adst_b1, es8, ed8);
    k_attn8<<<N_NODES*NHEADS/256, 256, 0, stream>>>(deg, ell, z8, es8, ed8, b_b1, h8);

    // ---- GATNet B, conv2 (160 -> 128) ----
    k_gemm<D160, HID, 128><<<N_NODES/128, dim3(16,64), D160*HID*4, stream>>>(h8, W_b2, zc);
    k_dot2<<<N_NODES/4, 256, 0, stream>>>(zc, asrc_b2, adst_b2, es1, ed1);
    k_attn1<<<N_NODES/4, 256, 0, stream>>>(deg, ell, zc, es1, ed1, b_b2, hc);   // hc = h4

    // ---- SAGPooling ----
    k_dot2<<<N_NODES/4, 256, 0, stream>>>(hc, w_rel, w_root, yrel, rroot);
    k_score<<<N_NODES/256, 256, 0, stream>>>(deg, ell, yrel, rroot, b_pool, score);
    k_topk_pool<<<NGRAPH, NPG, 0, stream>>>(score, hc, pooled, perm_f, sv, batch_f);
}

// Round 2
// 450.332 us; speedup vs baseline: 1.9010x; 1.9010x over previous
//
#include <hip/hip_runtime.h>
#include <math.h>

#define N_NODES 65536
#define NPG     512
#define NGRAPH  128
#define E_EDGES 524288
#define MAXDEG  64
#define NHEADS  8
#define F1      20
#define HID     128
#define D160    160
#define KSEL    256

__device__ __forceinline__ float lrelu(float x){ return x > 0.f ? x : 0.2f*x; }

__device__ __forceinline__ unsigned short f2bf(float f){
    unsigned int u = __float_as_uint(f);
    unsigned int r = (u + 0x7FFFu + ((u >> 16) & 1u)) >> 16;
    return (unsigned short)r;
}

typedef __attribute__((ext_vector_type(8))) short short8;
typedef __attribute__((ext_vector_type(4))) float f32x4;

// ---------------- ELL adjacency build (dst -> list of src) ----------------
__global__ void k_build_ell(const int* __restrict__ src, const int* __restrict__ dst,
                            int* __restrict__ deg, int* __restrict__ ell){
    int e = blockIdx.x*blockDim.x + threadIdx.x;
    if(e >= E_EDGES) return;
    int d = dst[e];
    int p = atomicAdd(&deg[d], 1);
    if(p < MAXDEG) ell[d*MAXDEG + p] = src[e];
}

// ---------------- conv A1: z from one-hot gather + es/ed dots ----------------
__global__ void k_a1_z(const int* __restrict__ x, const float* __restrict__ W,
                       const float* __restrict__ asrc, const float* __restrict__ adst,
                       float* __restrict__ z8, float* __restrict__ es8, float* __restrict__ ed8){
    int t = blockIdx.x*blockDim.x + threadIdx.x;
    if(t >= N_NODES*NHEADS) return;
    int n = t >> 3, h = t & 7;
    int lbl = x[n];
    const float* wrow = W + lbl*D160 + h*F1;
    const float* as = asrc + h*F1;
    const float* ad = adst + h*F1;
    float* zr = z8 + n*D160 + h*F1;
    float es = 0.f, ed = 0.f;
    #pragma unroll
    for(int f=0; f<F1; ++f){
        float v = wrow[f];
        zr[f] = v;
        es += v*as[f];
        ed += v*ad[f];
    }
    es8[t] = es; ed8[t] = ed;
}

// ---------------- es/ed dots for 8-head conv given z ----------------
__global__ void k_esed8(const float* __restrict__ z8, const float* __restrict__ asrc,
                        const float* __restrict__ adst,
                        float* __restrict__ es8, float* __restrict__ ed8){
    int t = blockIdx.x*blockDim.x + threadIdx.x;
    if(t >= N_NODES*NHEADS) return;
    int n = t >> 3, h = t & 7;
    const float* zr = z8 + n*D160 + h*F1;
    const float* as = asrc + h*F1;
    const float* ad = adst + h*F1;
    float es = 0.f, ed = 0.f;
    #pragma unroll
    for(int f=0; f<F1; ++f){
        float v = zr[f];
        es += v*as[f];
        ed += v*ad[f];
    }
    es8[t] = es; ed8[t] = ed;
}

// ---------------- 8-head attention aggregate (thread per node,head) ----------------
__global__ void k_attn8(const int* __restrict__ deg, const int* __restrict__ ell,
                        const float* __restrict__ z8, const float* __restrict__ es8,
                        const float* __restrict__ ed8, const float* __restrict__ bias,
                        float* __restrict__ out){
    int t = blockIdx.x*blockDim.x + threadIdx.x;
    if(t >= N_NODES*NHEADS) return;
    int n = t >> 3, h = t & 7;
    int dg = deg[n]; if(dg > MAXDEG) dg = MAXDEG;
    float edn = ed8[t];
    float eself = lrelu(es8[t] + edn);
    const int* el = ell + n*MAXDEG;
    float m = eself;
    for(int i=0;i<dg;++i){
        int s = el[i];
        float e = lrelu(es8[s*NHEADS + h] + edn);
        m = fmaxf(m, e);
    }
    float w = expf(eself - m);
    float den = w;
    float acc[F1];
    const float* zn = z8 + n*D160 + h*F1;
    #pragma unroll
    for(int f=0; f<F1; ++f) acc[f] = w*zn[f];
    for(int i=0;i<dg;++i){
        int s = el[i];
        float e = lrelu(es8[s*NHEADS + h] + edn);
        float wi = expf(e - m);
        den += wi;
        const float* zs = z8 + s*D160 + h*F1;
        #pragma unroll
        for(int f=0; f<F1; ++f) acc[f] += wi*zs[f];
    }
    float inv = 1.f/(den + 1e-16f);
    float* o = out + n*D160 + h*F1;
    const float* bb = bias + h*F1;
    #pragma unroll
    for(int f=0; f<F1; ++f) o[f] = fmaxf(acc[f]*inv + bb[f], 0.f);
}

// ---------------- bf16 MFMA GEMM: C[N,OUT] = A[N,IN] @ W[IN,OUT] ----------------
// W transposed+padded into LDS as bf16; A converted in-register.
// 4 waves/block, each wave: 16 rows x OUT cols. Block = 64 rows.
template<int IN, int OUT>
__global__ __launch_bounds__(256) void k_gemm_mfma(const float* __restrict__ A,
                                                   const float* __restrict__ W,
                                                   float* __restrict__ C){
    constexpr int NT = OUT/16;      // col tiles
    constexpr int KS = IN/32;       // k steps
    constexpr int LDW = IN + 8;     // padded bf16 row stride (16B-aligned, bank-spread)
    __shared__ __align__(16) unsigned short Wt[OUT*LDW];
    int tid = threadIdx.x;
    for(int i = tid; i < IN*OUT; i += 256){
        int k = i / OUT, n = i - k*OUT;
        Wt[n*LDW + k] = f2bf(W[i]);
    }
    __syncthreads();
    int wave = tid >> 6, lane = tid & 63;
    int col16 = lane & 15;
    int kq = (lane >> 4) * 8;
    int row = blockIdx.x*64 + wave*16 + col16;    // A row for this lane
    const float* Ar = A + (size_t)row*IN + kq;
    f32x4 acc[NT];
    #pragma unroll
    for(int c=0;c<NT;++c) acc[c] = (f32x4){0.f,0.f,0.f,0.f};
    #pragma unroll
    for(int ks=0; ks<KS; ++ks){
        float4 a0 = *reinterpret_cast<const float4*>(Ar + ks*32);
        float4 a1 = *reinterpret_cast<const float4*>(Ar + ks*32 + 4);
        short8 af;
        af[0]=(short)f2bf(a0.x); af[1]=(short)f2bf(a0.y);
        af[2]=(short)f2bf(a0.z); af[3]=(short)f2bf(a0.w);
        af[4]=(short)f2bf(a1.x); af[5]=(short)f2bf(a1.y);
        af[6]=(short)f2bf(a1.z); af[7]=(short)f2bf(a1.w);
        #pragma unroll
        for(int c=0;c<NT;++c){
            short8 bf = *reinterpret_cast<const short8*>(&Wt[(c*16 + col16)*LDW + ks*32 + kq]);
            acc[c] = __builtin_amdgcn_mfma_f32_16x16x32_bf16(af, bf, acc[c], 0, 0, 0);
        }
    }
    int rbase = blockIdx.x*64 + wave*16 + (lane >> 4)*4;
    #pragma unroll
    for(int c=0;c<NT;++c){
        #pragma unroll
        for(int r=0;r<4;++r){
            C[(size_t)(rbase + r)*OUT + c*16 + col16] = acc[c][r];
        }
    }
}

// ---------------- two dots per node over HID dims (wave per node) ----------------
__global__ void k_dot2(const float* __restrict__ Z, const float* __restrict__ va,
                       const float* __restrict__ vb, float* __restrict__ oa,
                       float* __restrict__ ob){
    int gt = blockIdx.x*blockDim.x + threadIdx.x;
    int n = gt >> 6;
    int l = threadIdx.x & 63;
    if(n >= N_NODES) return;
    const float* z = Z + (size_t)n*HID;
    float pa = z[l]*va[l] + z[l+64]*va[l+64];
    float pb = z[l]*vb[l] + z[l+64]*vb[l+64];
    for(int o=32;o>0;o>>=1){ pa += __shfl_xor(pa,o); pb += __shfl_xor(pb,o); }
    if(l==0){ oa[n]=pa; ob[n]=pb; }
}

// ---------------- 1-head attention aggregate (wave per node) ----------------
__global__ void k_attn1(const int* __restrict__ deg, const int* __restrict__ ell,
                        const float* __restrict__ Z, const float* __restrict__ es,
                        const float* __restrict__ ed, const float* __restrict__ bias,
                        float* __restrict__ out){
    int gt = blockIdx.x*blockDim.x + threadIdx.x;
    int n = gt >> 6;
    int l = threadIdx.x & 63;
    if(n >= N_NODES) return;
    int dg = deg[n]; if(dg > MAXDEG) dg = MAXDEG;
    float edn = ed[n];
    float eself = lrelu(es[n] + edn);
    int s_l = 0; float e_l = -1e30f;
    if(l < dg){ s_l = ell[n*MAXDEG + l]; e_l = lrelu(es[s_l] + edn); }
    float m = fmaxf(e_l, eself);
    for(int o=32;o>0;o>>=1) m = fmaxf(m, __shfl_xor(m,o));
    float w_l = (l < dg) ? expf(e_l - m) : 0.f;
    float den = w_l;
    for(int o=32;o>0;o>>=1) den += __shfl_xor(den,o);
    float wself = expf(eself - m);
    den += wself;
    float acc0 = wself*Z[(size_t)n*HID + l];
    float acc1 = wself*Z[(size_t)n*HID + 64 + l];
    for(int i=0;i<dg;++i){
        int s = __shfl(s_l, i);
        float w = __shfl(w_l, i);
        acc0 += w*Z[(size_t)s*HID + l];
        acc1 += w*Z[(size_t)s*HID + 64 + l];
    }
    float inv = 1.f/(den + 1e-16f);
    out[(size_t)n*HID + l]      = fmaxf(acc0*inv + bias[l],      0.f);
    out[(size_t)n*HID + 64 + l] = fmaxf(acc1*inv + bias[64 + l], 0.f);
}

// ---------------- pooling score: tanh(sum_nbr y[s] + r[n] + b) ----------------
__global__ void k_score(const int* __restrict__ deg, const int* __restrict__ ell,
                        const float* __restrict__ yrel, const float* __restrict__ rroot,
                        const float* __restrict__ bpool, float* __restrict__ score){
    int n = blockIdx.x*blockDim.x + threadIdx.x;
    if(n >= N_NODES) return;
    int dg = deg[n]; if(dg > MAXDEG) dg = MAXDEG;
    float s = rroot[n] + bpool[0];
    const int* el = ell + n*MAXDEG;
    for(int i=0;i<dg;++i) s += yrel[el[i]];
    score[n] = tanhf(s);
}

// ---------------- per-graph top-k (bitonic, desc by score, tie asc idx) + pooled max ----------------
__global__ void k_topk_pool(const float* __restrict__ score, const float* __restrict__ H,
                            float* __restrict__ pooled, float* __restrict__ perm_f,
                            float* __restrict__ sv, float* __restrict__ batch_f){
    __shared__ float skey[NPG];
    __shared__ int   sidx[NPG];
    int g = blockIdx.x;
    int t = threadIdx.x;
    int base = g*NPG;
    skey[t] = score[base + t];
    sidx[t] = t;
    __syncthreads();
    for(int k=2; k<=NPG; k<<=1){
        for(int j=k>>1; j>0; j>>=1){
            int ixj = t ^ j;
            if(ixj > t){
                float ka = skey[t], kb = skey[ixj];
                int   ia = sidx[t], ib = sidx[ixj];
                bool up = ((t & k) == 0);
                bool t_after = (ka < kb) || (ka == kb && ia > ib);
                if(t_after == up){
                    skey[t] = kb; skey[ixj] = ka;
                    sidx[t] = ib; sidx[ixj] = ia;
                }
            }
            __syncthreads();
        }
    }
    if(t < KSEL){
        perm_f[g*KSEL + t]  = (float)(base + sidx[t]);
        sv[g*KSEL + t]      = skey[t];
        batch_f[g*KSEL + t] = (float)g;
    }
    __syncthreads();
    if(t < HID){
        float mx = -1e30f;
        for(int kk=0; kk<KSEL; ++kk){
            float v = H[(size_t)(base + sidx[kk])*HID + t] * skey[kk];
            mx = fmaxf(mx, v);
        }
        pooled[g*HID + t] = mx;
    }
}

extern "C" void kernel_launch(void* const* d_in, const int* in_sizes, int n_in,
                              void* d_out, int out_size, void* d_ws, size_t ws_size,
                              hipStream_t stream) {
    const int*   x       = (const int*)  d_in[0];
    const int*   eidx    = (const int*)  d_in[1];
    const float* W_a1    = (const float*)d_in[3];
    const float* asrc_a1 = (const float*)d_in[4];
    const float* adst_a1 = (const float*)d_in[5];
    const float* b_a1    = (const float*)d_in[6];
    const float* W_a2    = (const float*)d_in[7];
    const float* asrc_a2 = (const float*)d_in[8];
    const float* adst_a2 = (const float*)d_in[9];
    const float* b_a2    = (const float*)d_in[10];
    const float* W_b1    = (const float*)d_in[11];
    const float* asrc_b1 = (const float*)d_in[12];
    const float* adst_b1 = (const float*)d_in[13];
    const float* b_b1    = (const float*)d_in[14];
    const float* W_b2    = (const float*)d_in[15];
    const float* asrc_b2 = (const float*)d_in[16];
    const float* adst_b2 = (const float*)d_in[17];
    const float* b_b2    = (const float*)d_in[18];
    const float* w_rel   = (const float*)d_in[19];
    const float* w_root  = (const float*)d_in[20];
    const float* b_pool  = (const float*)d_in[21];

    const int* e_src = eidx;
    const int* e_dst = eidx + E_EDGES;

    char* ws = (char*)d_ws;
    size_t off = 0;
    auto alloc = [&](size_t bytes)->char*{
        char* p = ws + off;
        off += (bytes + 255) & ~(size_t)255;
        return p;
    };
    int*   deg   = (int*)  alloc((size_t)N_NODES*4);
    int*   ell   = (int*)  alloc((size_t)N_NODES*MAXDEG*4);
    float* z8    = (float*)alloc((size_t)N_NODES*D160*4);
    float* h8    = (float*)alloc((size_t)N_NODES*D160*4);
    float* zc    = (float*)alloc((size_t)N_NODES*HID*4);
    float* hc    = (float*)alloc((size_t)N_NODES*HID*4);
    float* es8   = (float*)alloc((size_t)N_NODES*NHEADS*4);
    float* ed8   = (float*)alloc((size_t)N_NODES*NHEADS*4);
    float* es1   = (float*)alloc((size_t)N_NODES*4);
    float* ed1   = (float*)alloc((size_t)N_NODES*4);
    float* yrel  = (float*)alloc((size_t)N_NODES*4);
    float* rroot = (float*)alloc((size_t)N_NODES*4);
    float* score = (float*)alloc((size_t)N_NODES*4);
    (void)ws_size; (void)n_in; (void)in_sizes; (void)out_size;

    float* out      = (float*)d_out;
    float* pooled   = out;                        // 128*128
    float* perm_f   = out + NGRAPH*HID;           // 32768
    float* sv       = perm_f + NGRAPH*KSEL;       // 32768
    float* batch_f  = sv + NGRAPH*KSEL;           // 32768

    hipMemsetAsync(deg, 0, (size_t)N_NODES*4, stream);
    k_build_ell<<<E_EDGES/256, 256, 0, stream>>>(e_src, e_dst, deg, ell);

    // ---- GATNet A, conv1 (D=100 -> 20x8) ----
    k_a1_z<<<N_NODES*NHEADS/256, 256, 0, stream>>>(x, W_a1, asrc_a1, adst_a1, z8, es8, ed8);
    k_attn8<<<N_NODES*NHEADS/256, 256, 0, stream>>>(deg, ell, z8, es8, ed8, b_a1, h8);

    // ---- GATNet A, conv2 (160 -> 128) ----
    k_gemm_mfma<D160, HID><<<N_NODES/64, 256, 0, stream>>>(h8, W_a2, zc);
    k_dot2<<<N_NODES/4, 256, 0, stream>>>(zc, asrc_a2, adst_a2, es1, ed1);
    k_attn1<<<N_NODES/4, 256, 0, stream>>>(deg, ell, zc, es1, ed1, b_a2, hc);

    // ---- GATNet B, conv1 (128 -> 20x8) ----
    k_gemm_mfma<HID, D160><<<N_NODES/64, 256, 0, stream>>>(hc, W_b1, z8);
    k_esed8<<<N_NODES*NHEADS/256, 256, 0, stream>>>(z8, asrc_b1, adst_b1, es8, ed8);
    k_attn8<<<N_NODES*NHEADS/256, 256, 0, stream>>>(deg, ell, z8, es8, ed8, b_b1, h8);

    // ---- GATNet B, conv2 (160 -> 128) ----
    k_gemm_mfma<D160, HID><<<N_NODES/64, 256, 0, stream>>>(h8, W_b2, zc);
    k_dot2<<<N_NODES/4, 256, 0, stream>>>(zc, asrc_b2, adst_b2, es1, ed1);
    k_attn1<<<N_NODES/4, 256, 0, stream>>>(deg, ell, zc, es1, ed1, b_b2, hc);   // hc = h4

    // ---- SAGPooling ----
    k_dot2<<<N_NODES/4, 256, 0, stream>>>(hc, w_rel, w_root, yrel, rroot);
    k_score<<<N_NODES/256, 256, 0, stream>>>(deg, ell, yrel, rroot, b_pool, score);
    k_topk_pool<<<NGRAPH, NPG, 0, stream>>>(score, hc, pooled, perm_f, sv, batch_f);
}

// Round 3
// 314.782 us; speedup vs baseline: 2.7196x; 1.4306x over previous
//
#include <hip/hip_runtime.h>
#include <math.h>

#define N_NODES 65536
#define NPG     512
#define NGRAPH  128
#define E_EDGES 524288
#define MAXDEG  64
#define NHEADS  8
#define F1      20
#define HID     128
#define D160    160
#define KSEL    256

typedef unsigned short ushort_t;
typedef unsigned int   uint_t;
typedef __attribute__((ext_vector_type(8))) short short8;
typedef __attribute__((ext_vector_type(4))) float f32x4;

__device__ __forceinline__ float lrelu(float x){ return x > 0.f ? x : 0.2f*x; }
__device__ __forceinline__ ushort_t f2bf(float f){
    uint_t u = __float_as_uint(f);
    return (ushort_t)((u + 0x7FFFu + ((u >> 16) & 1u)) >> 16);
}
__device__ __forceinline__ float bf2f(ushort_t u){ return __uint_as_float(((uint_t)u) << 16); }
// XCD-coherent block swizzle: blocks with bid%8==r run on XCD r; give them a
// contiguous chunk of work so each graph's tiles live on exactly one XCD's L2.
__device__ __forceinline__ int xswz(int bid, int nblocks){
    return (bid & 7) * (nblocks >> 3) + (bid >> 3);
}

// ---------------- ELL adjacency build (dst -> list of src) ----------------
__global__ void k_build_ell(const int* __restrict__ src, const int* __restrict__ dst,
                            int* __restrict__ deg, int* __restrict__ ell){
    int blk = xswz(blockIdx.x, E_EDGES/256);
    int e = blk*blockDim.x + threadIdx.x;
    int d = dst[e];
    int p = atomicAdd(&deg[d], 1);
    if(p < MAXDEG) ell[d*MAXDEG + p] = src[e];
}

// ---------------- conv A1: z (bf16) from one-hot gather + es/ed dots ----------------
__global__ void k_a1_z(const int* __restrict__ x, const float* __restrict__ W,
                       const float* __restrict__ asrc, const float* __restrict__ adst,
                       ushort_t* __restrict__ z8, float* __restrict__ es8, float* __restrict__ ed8){
    int blk = xswz(blockIdx.x, N_NODES*NHEADS/256);
    int t = blk*blockDim.x + threadIdx.x;
    int n = t >> 3, h = t & 7;
    int lbl = x[n];
    const float* wrow = W + lbl*D160 + h*F1;
    const float* as = asrc + h*F1;
    const float* ad = adst + h*F1;
    uint_t* zr = (uint_t*)(z8 + (size_t)n*D160 + h*F1);  // 40h bytes, 4B-aligned
    float es = 0.f, ed = 0.f;
    #pragma unroll
    for(int f=0; f<10; ++f){
        float v0 = wrow[2*f], v1 = wrow[2*f+1];
        zr[f] = (uint_t)f2bf(v0) | ((uint_t)f2bf(v1) << 16);
        es += v0*as[2*f] + v1*as[2*f+1];
        ed += v0*ad[2*f] + v1*ad[2*f+1];
    }
    es8[t] = es; ed8[t] = ed;
}

// ---------------- es/ed dots for 8-head conv given bf16 z ----------------
__global__ void k_esed8(const ushort_t* __restrict__ z8, const float* __restrict__ asrc,
                        const float* __restrict__ adst,
                        float* __restrict__ es8, float* __restrict__ ed8){
    int blk = xswz(blockIdx.x, N_NODES*NHEADS/256);
    int t = blk*blockDim.x + threadIdx.x;
    int n = t >> 3, h = t & 7;
    const uint_t* zr = (const uint_t*)(z8 + (size_t)n*D160 + h*F1);
    const float* as = asrc + h*F1;
    const float* ad = adst + h*F1;
    float es = 0.f, ed = 0.f;
    #pragma unroll
    for(int f=0; f<10; ++f){
        uint_t v = zr[f];
        float v0 = bf2f((ushort_t)(v & 0xFFFF)), v1 = bf2f((ushort_t)(v >> 16));
        es += v0*as[2*f] + v1*as[2*f+1];
        ed += v0*ad[2*f] + v1*ad[2*f+1];
    }
    es8[t] = es; ed8[t] = ed;
}

// ---------------- 8-head attention aggregate (thread per node,head), bf16 z ----------------
__global__ void k_attn8(const int* __restrict__ deg, const int* __restrict__ ell,
                        const ushort_t* __restrict__ z8, const float* __restrict__ es8,
                        const float* __restrict__ ed8, const float* __restrict__ bias,
                        ushort_t* __restrict__ out){
    int blk = xswz(blockIdx.x, N_NODES*NHEADS/256);
    int t = blk*blockDim.x + threadIdx.x;
    int n = t >> 3, h = t & 7;
    int dg = deg[n]; if(dg > MAXDEG) dg = MAXDEG;
    float edn = ed8[t];
    float eself = lrelu(es8[t] + edn);
    const int* el = ell + n*MAXDEG;
    float m = eself;
    for(int i=0;i<dg;++i){
        int s = el[i];
        float e = lrelu(es8[s*NHEADS + h] + edn);
        m = fmaxf(m, e);
    }
    float w = expf(eself - m);
    float den = w;
    float acc[F1];
    const uint_t* zn = (const uint_t*)(z8 + (size_t)n*D160 + h*F1);
    #pragma unroll
    for(int f=0; f<10; ++f){
        uint_t v = zn[f];
        acc[2*f]   = w*bf2f((ushort_t)(v & 0xFFFF));
        acc[2*f+1] = w*bf2f((ushort_t)(v >> 16));
    }
    for(int i=0;i<dg;++i){
        int s = el[i];
        float e = lrelu(es8[s*NHEADS + h] + edn);
        float wi = expf(e - m);
        den += wi;
        const uint_t* zs = (const uint_t*)(z8 + (size_t)s*D160 + h*F1);
        #pragma unroll
        for(int f=0; f<10; ++f){
            uint_t v = zs[f];
            acc[2*f]   += wi*bf2f((ushort_t)(v & 0xFFFF));
            acc[2*f+1] += wi*bf2f((ushort_t)(v >> 16));
        }
    }
    float inv = 1.f/(den + 1e-16f);
    uint_t* o = (uint_t*)(out + (size_t)n*D160 + h*F1);
    const float* bb = bias + h*F1;
    #pragma unroll
    for(int f=0; f<10; ++f){
        float v0 = fmaxf(acc[2*f]*inv   + bb[2*f],   0.f);
        float v1 = fmaxf(acc[2*f+1]*inv + bb[2*f+1], 0.f);
        o[f] = (uint_t)f2bf(v0) | ((uint_t)f2bf(v1) << 16);
    }
}

// ---------------- bf16 MFMA GEMM: C[N,OUT](bf16) = A[N,IN](bf16) @ W[IN,OUT](f32) ----
// Optional fused epilogue: oa[row]=C_row . va, ob[row]=C_row . vb (f32, from acc).
template<int IN, int OUT, bool DOT>
__global__ __launch_bounds__(256) void k_gemm_mfma(const ushort_t* __restrict__ A,
                                                   const float* __restrict__ W,
                                                   ushort_t* __restrict__ C,
                                                   const float* __restrict__ va,
                                                   const float* __restrict__ vb,
                                                   float* __restrict__ oa,
                                                   float* __restrict__ ob){
    constexpr int NT = OUT/16;
    constexpr int KS = IN/32;
    constexpr int LDW = IN + 8;
    __shared__ __align__(16) ushort_t Wt[OUT*LDW];
    int tid = threadIdx.x;
    for(int i = tid; i < IN*OUT; i += 256){
        int k = i / OUT, n = i - k*OUT;
        Wt[n*LDW + k] = f2bf(W[i]);
    }
    __syncthreads();
    int blk = xswz(blockIdx.x, N_NODES/64);
    int wave = tid >> 6, lane = tid & 63;
    int col16 = lane & 15;
    int kq = (lane >> 4) * 8;
    int row = blk*64 + wave*16 + col16;
    const ushort_t* Ar = A + (size_t)row*IN + kq;
    f32x4 acc[NT];
    #pragma unroll
    for(int c=0;c<NT;++c) acc[c] = (f32x4){0.f,0.f,0.f,0.f};
    #pragma unroll
    for(int ks=0; ks<KS; ++ks){
        short8 af = *reinterpret_cast<const short8*>(Ar + ks*32);
        #pragma unroll
        for(int c=0;c<NT;++c){
            short8 bf = *reinterpret_cast<const short8*>(&Wt[(c*16 + col16)*LDW + ks*32 + kq]);
            acc[c] = __builtin_amdgcn_mfma_f32_16x16x32_bf16(af, bf, acc[c], 0, 0, 0);
        }
    }
    int rbase = blk*64 + wave*16 + (lane >> 4)*4;
    #pragma unroll
    for(int c=0;c<NT;++c){
        #pragma unroll
        for(int r=0;r<4;++r){
            C[(size_t)(rbase + r)*OUT + c*16 + col16] = f2bf(acc[c][r]);
        }
    }
    if(DOT){
        float pa[4] = {0,0,0,0}, pb[4] = {0,0,0,0};
        #pragma unroll
        for(int c=0;c<NT;++c){
            float a = va[c*16 + col16];
            float b = vb[c*16 + col16];
            #pragma unroll
            for(int r=0;r<4;++r){ pa[r] += acc[c][r]*a; pb[r] += acc[c][r]*b; }
        }
        #pragma unroll
        for(int o=1;o<16;o<<=1){
            #pragma unroll
            for(int r=0;r<4;++r){ pa[r] += __shfl_xor(pa[r], o); pb[r] += __shfl_xor(pb[r], o); }
        }
        if(col16 == 0){
            #pragma unroll
            for(int r=0;r<4;++r){ oa[rbase + r] = pa[r]; ob[rbase + r] = pb[r]; }
        }
    }
}

// ---------------- 1-head attention aggregate (wave per node), bf16 Z ----------------
template<typename OutT>
__global__ void k_attn1(const int* __restrict__ deg, const int* __restrict__ ell,
                        const ushort_t* __restrict__ Z, const float* __restrict__ es,
                        const float* __restrict__ ed, const float* __restrict__ bias,
                        OutT* __restrict__ out){
    int blk = xswz(blockIdx.x, N_NODES/4);
    int gt = blk*blockDim.x + threadIdx.x;
    int n = gt >> 6;
    int l = threadIdx.x & 63;
    int dg = deg[n]; if(dg > MAXDEG) dg = MAXDEG;
    float edn = ed[n];
    float eself = lrelu(es[n] + edn);
    int s_l = 0; float e_l = -1e30f;
    if(l < dg){ s_l = ell[n*MAXDEG + l]; e_l = lrelu(es[s_l] + edn); }
    float m = fmaxf(e_l, eself);
    for(int o=32;o>0;o>>=1) m = fmaxf(m, __shfl_xor(m,o));
    float w_l = (l < dg) ? expf(e_l - m) : 0.f;
    float den = w_l;
    for(int o=32;o>0;o>>=1) den += __shfl_xor(den,o);
    float wself = expf(eself - m);
    den += wself;
    float acc0 = wself*bf2f(Z[(size_t)n*HID + l]);
    float acc1 = wself*bf2f(Z[(size_t)n*HID + 64 + l]);
    for(int i=0;i<dg;++i){
        int s = __shfl(s_l, i);
        float w = __shfl(w_l, i);
        acc0 += w*bf2f(Z[(size_t)s*HID + l]);
        acc1 += w*bf2f(Z[(size_t)s*HID + 64 + l]);
    }
    float inv = 1.f/(den + 1e-16f);
    float r0 = fmaxf(acc0*inv + bias[l],      0.f);
    float r1 = fmaxf(acc1*inv + bias[64 + l], 0.f);
    if(sizeof(OutT) == 2){
        ((ushort_t*)out)[(size_t)n*HID + l]      = f2bf(r0);
        ((ushort_t*)out)[(size_t)n*HID + 64 + l] = f2bf(r1);
    } else {
        ((float*)out)[(size_t)n*HID + l]      = r0;
        ((float*)out)[(size_t)n*HID + 64 + l] = r1;
    }
}

// ---------------- two dots per node over HID dims (wave per node), f32 Z ----------------
__global__ void k_dot2(const float* __restrict__ Z, const float* __restrict__ va,
                       const float* __restrict__ vb, float* __restrict__ oa,
                       float* __restrict__ ob){
    int blk = xswz(blockIdx.x, N_NODES/4);
    int gt = blk*blockDim.x + threadIdx.x;
    int n = gt >> 6;
    int l = threadIdx.x & 63;
    const float* z = Z + (size_t)n*HID;
    float pa = z[l]*va[l] + z[l+64]*va[l+64];
    float pb = z[l]*vb[l] + z[l+64]*vb[l+64];
    for(int o=32;o>0;o>>=1){ pa += __shfl_xor(pa,o); pb += __shfl_xor(pb,o); }
    if(l==0){ oa[n]=pa; ob[n]=pb; }
}

// ---------------- pooling score ----------------
__global__ void k_score(const int* __restrict__ deg, const int* __restrict__ ell,
                        const float* __restrict__ yrel, const float* __restrict__ rroot,
                        const float* __restrict__ bpool, float* __restrict__ score){
    int blk = xswz(blockIdx.x, N_NODES/256);
    int n = blk*blockDim.x + threadIdx.x;
    int dg = deg[n]; if(dg > MAXDEG) dg = MAXDEG;
    float s = rroot[n] + bpool[0];
    const int* el = ell + n*MAXDEG;
    for(int i=0;i<dg;++i) s += yrel[el[i]];
    score[n] = tanhf(s);
}

// ---------------- per-graph top-k + pooled max ----------------
__global__ void k_topk_pool(const float* __restrict__ score, const float* __restrict__ H,
                            float* __restrict__ pooled, float* __restrict__ perm_f,
                            float* __restrict__ sv, float* __restrict__ batch_f){
    __shared__ float skey[NPG];
    __shared__ int   sidx[NPG];
    int g = xswz(blockIdx.x, NGRAPH);
    int t = threadIdx.x;
    int base = g*NPG;
    skey[t] = score[base + t];
    sidx[t] = t;
    __syncthreads();
    for(int k=2; k<=NPG; k<<=1){
        for(int j=k>>1; j>0; j>>=1){
            int ixj = t ^ j;
            if(ixj > t){
                float ka = skey[t], kb = skey[ixj];
                int   ia = sidx[t], ib = sidx[ixj];
                bool up = ((t & k) == 0);
                bool t_after = (ka < kb) || (ka == kb && ia > ib);
                if(t_after == up){
                    skey[t] = kb; skey[ixj] = ka;
                    sidx[t] = ib; sidx[ixj] = ia;
                }
            }
            __syncthreads();
        }
    }
    if(t < KSEL){
        perm_f[g*KSEL + t]  = (float)(base + sidx[t]);
        sv[g*KSEL + t]      = skey[t];
        batch_f[g*KSEL + t] = (float)g;
    }
    __syncthreads();
    if(t < HID){
        float mx = -1e30f;
        for(int kk=0; kk<KSEL; ++kk){
            float v = H[(size_t)(base + sidx[kk])*HID + t] * skey[kk];
            mx = fmaxf(mx, v);
        }
        pooled[g*HID + t] = mx;
    }
}

extern "C" void kernel_launch(void* const* d_in, const int* in_sizes, int n_in,
                              void* d_out, int out_size, void* d_ws, size_t ws_size,
                              hipStream_t stream) {
    const int*   x       = (const int*)  d_in[0];
    const int*   eidx    = (const int*)  d_in[1];
    const float* W_a1    = (const float*)d_in[3];
    const float* asrc_a1 = (const float*)d_in[4];
    const float* adst_a1 = (const float*)d_in[5];
    const float* b_a1    = (const float*)d_in[6];
    const float* W_a2    = (const float*)d_in[7];
    const float* asrc_a2 = (const float*)d_in[8];
    const float* adst_a2 = (const float*)d_in[9];
    const float* b_a2    = (const float*)d_in[10];
    const float* W_b1    = (const float*)d_in[11];
    const float* asrc_b1 = (const float*)d_in[12];
    const float* adst_b1 = (const float*)d_in[13];
    const float* b_b1    = (const float*)d_in[14];
    const float* W_b2    = (const float*)d_in[15];
    const float* asrc_b2 = (const float*)d_in[16];
    const float* adst_b2 = (const float*)d_in[17];
    const float* b_b2    = (const float*)d_in[18];
    const float* w_rel   = (const float*)d_in[19];
    const float* w_root  = (const float*)d_in[20];
    const float* b_pool  = (const float*)d_in[21];

    const int* e_src = eidx;
    const int* e_dst = eidx + E_EDGES;

    char* ws = (char*)d_ws;
    size_t off = 0;
    auto alloc = [&](size_t bytes)->char*{
        char* p = ws + off;
        off += (bytes + 255) & ~(size_t)255;
        return p;
    };
    int*      deg   = (int*)     alloc((size_t)N_NODES*4);
    int*      ell   = (int*)     alloc((size_t)N_NODES*MAXDEG*4);
    ushort_t* z8    = (ushort_t*)alloc((size_t)N_NODES*D160*2);
    ushort_t* h8    = (ushort_t*)alloc((size_t)N_NODES*D160*2);
    ushort_t* zc    = (ushort_t*)alloc((size_t)N_NODES*HID*2);
    ushort_t* hmid  = (ushort_t*)alloc((size_t)N_NODES*HID*2);
    float*    hfin  = (float*)   alloc((size_t)N_NODES*HID*4);
    float*    es8   = (float*)   alloc((size_t)N_NODES*NHEADS*4);
    float*    ed8   = (float*)   alloc((size_t)N_NODES*NHEADS*4);
    float*    es1   = (float*)   alloc((size_t)N_NODES*4);
    float*    ed1   = (float*)   alloc((size_t)N_NODES*4);
    float*    yrel  = (float*)   alloc((size_t)N_NODES*4);
    float*    rroot = (float*)   alloc((size_t)N_NODES*4);
    float*    score = (float*)   alloc((size_t)N_NODES*4);
    (void)ws_size; (void)n_in; (void)in_sizes; (void)out_size;

    float* out      = (float*)d_out;
    float* pooled   = out;
    float* perm_f   = out + NGRAPH*HID;
    float* sv       = perm_f + NGRAPH*KSEL;
    float* batch_f  = sv + NGRAPH*KSEL;

    hipMemsetAsync(deg, 0, (size_t)N_NODES*4, stream);
    k_build_ell<<<E_EDGES/256, 256, 0, stream>>>(e_src, e_dst, deg, ell);

    // ---- GATNet A, conv1 (one-hot gather -> 20x8) ----
    k_a1_z<<<N_NODES*NHEADS/256, 256, 0, stream>>>(x, W_a1, asrc_a1, adst_a1, z8, es8, ed8);
    k_attn8<<<N_NODES*NHEADS/256, 256, 0, stream>>>(deg, ell, z8, es8, ed8, b_a1, h8);

    // ---- GATNet A, conv2 (160 -> 128) + fused es/ed dots ----
    k_gemm_mfma<D160, HID, true><<<N_NODES/64, 256, 0, stream>>>(h8, W_a2, zc, asrc_a2, adst_a2, es1, ed1);
    k_attn1<ushort_t><<<N_NODES/4, 256, 0, stream>>>(deg, ell, zc, es1, ed1, b_a2, hmid);

    // ---- GATNet B, conv1 (128 -> 20x8) ----
    k_gemm_mfma<HID, D160, false><<<N_NODES/64, 256, 0, stream>>>(hmid, W_b1, z8, nullptr, nullptr, nullptr, nullptr);
    k_esed8<<<N_NODES*NHEADS/256, 256, 0, stream>>>(z8, asrc_b1, adst_b1, es8, ed8);
    k_attn8<<<N_NODES*NHEADS/256, 256, 0, stream>>>(deg, ell, z8, es8, ed8, b_b1, h8);

    // ---- GATNet B, conv2 (160 -> 128) + fused es/ed dots ----
    k_gemm_mfma<D160, HID, true><<<N_NODES/64, 256, 0, stream>>>(h8, W_b2, zc, asrc_b2, adst_b2, es1, ed1);
    k_attn1<float><<<N_NODES/4, 256, 0, stream>>>(deg, ell, zc, es1, ed1, b_b2, hfin);

    // ---- SAGPooling ----
    k_dot2<<<N_NODES/4, 256, 0, stream>>>(hfin, w_rel, w_root, yrel, rroot);
    k_score<<<N_NODES/256, 256, 0, stream>>>(deg, ell, yrel, rroot, b_pool, score);
    k_topk_pool<<<NGRAPH, NPG, 0, stream>>>(score, hfin, pooled, perm_f, sv, batch_f);
}

// Round 4
// 270.156 us; speedup vs baseline: 3.1689x; 1.1652x over previous
//
#include <hip/hip_runtime.h>
#include <math.h>

#define N_NODES 65536
#define NPG     512
#define NGRAPH  128
#define E_EDGES 524288
#define MAXDEG  64
#define NHEADS  8
#define F1      20
#define HID     128
#define D160    160
#define KSEL    256

typedef unsigned short ushort_t;
typedef unsigned int   uint_t;
typedef unsigned long long u64;
typedef __attribute__((ext_vector_type(8))) short short8;
typedef __attribute__((ext_vector_type(4))) float f32x4;

__device__ __forceinline__ float lrelu(float x){ return x > 0.f ? x : 0.2f*x; }
__device__ __forceinline__ ushort_t f2bf(float f){
    uint_t u = __float_as_uint(f);
    return (ushort_t)((u + 0x7FFFu + ((u >> 16) & 1u)) >> 16);
}
__device__ __forceinline__ float bf2f(ushort_t u){ return __uint_as_float(((uint_t)u) << 16); }
// XCD-coherent block swizzle: graph tiles pinned to one XCD across ALL kernels.
__device__ __forceinline__ int xswz(int bid, int nblocks){
    return (bid & 7) * (nblocks >> 3) + (bid >> 3);
}

// sortable composite: desc score, tie -> asc idx
__device__ __forceinline__ u64 comp_make(float s, int idx){
    uint_t u = __float_as_uint(s);
    u ^= (u & 0x80000000u) ? 0xFFFFFFFFu : 0x80000000u;
    return ((u64)u << 32) | (u64)(511 - idx);
}
__device__ __forceinline__ float comp_score(u64 c){
    uint_t u = (uint_t)(c >> 32);
    u ^= (u & 0x80000000u) ? 0x80000000u : 0xFFFFFFFFu;
    return __uint_as_float(u);
}
__device__ __forceinline__ int comp_idx(u64 c){ return 511 - (int)(c & 0x1FFu); }
__device__ __forceinline__ u64 shfl_xor_u64(u64 x, int m){
    uint_t lo = __shfl_xor((uint_t)x, m);
    uint_t hi = __shfl_xor((uint_t)(x >> 32), m);
    return ((u64)hi << 32) | lo;
}

// ---------------- ELL adjacency build (dst -> list of src) ----------------
__global__ void k_build_ell(const int* __restrict__ src, const int* __restrict__ dst,
                            int* __restrict__ deg, int* __restrict__ ell){
    int blk = xswz(blockIdx.x, E_EDGES/256);
    int e = blk*blockDim.x + threadIdx.x;
    int d = dst[e];
    int p = atomicAdd(&deg[d], 1);
    if(p < MAXDEG) ell[d*MAXDEG + p] = src[e];
}

// ---------------- conv A1: z (bf16) from one-hot gather + es/ed dots ----------------
__global__ void k_a1_z(const int* __restrict__ x, const float* __restrict__ W,
                       const float* __restrict__ asrc, const float* __restrict__ adst,
                       ushort_t* __restrict__ z8, float* __restrict__ es8, float* __restrict__ ed8){
    int blk = xswz(blockIdx.x, N_NODES*NHEADS/256);
    int t = blk*blockDim.x + threadIdx.x;
    int n = t >> 3, h = t & 7;
    int lbl = x[n];
    const float* wrow = W + lbl*D160 + h*F1;
    const float* as = asrc + h*F1;
    const float* ad = adst + h*F1;
    uint_t* zr = (uint_t*)(z8 + (size_t)n*D160 + h*F1);
    float es = 0.f, ed = 0.f;
    #pragma unroll
    for(int f=0; f<10; ++f){
        float v0 = wrow[2*f], v1 = wrow[2*f+1];
        zr[f] = (uint_t)f2bf(v0) | ((uint_t)f2bf(v1) << 16);
        es += v0*as[2*f] + v1*as[2*f+1];
        ed += v0*ad[2*f] + v1*ad[2*f+1];
    }
    es8[t] = es; ed8[t] = ed;
}

// ---------------- es/ed dots for 8-head conv given bf16 z ----------------
__global__ void k_esed8(const ushort_t* __restrict__ z8, const float* __restrict__ asrc,
                        const float* __restrict__ adst,
                        float* __restrict__ es8, float* __restrict__ ed8){
    int blk = xswz(blockIdx.x, N_NODES*NHEADS/256);
    int t = blk*blockDim.x + threadIdx.x;
    int n = t >> 3, h = t & 7;
    const uint_t* zr = (const uint_t*)(z8 + (size_t)n*D160 + h*F1);
    const float* as = asrc + h*F1;
    const float* ad = adst + h*F1;
    float es = 0.f, ed = 0.f;
    #pragma unroll
    for(int f=0; f<10; ++f){
        uint_t v = zr[f];
        float v0 = bf2f((ushort_t)(v & 0xFFFF)), v1 = bf2f((ushort_t)(v >> 16));
        es += v0*as[2*f] + v1*as[2*f+1];
        ed += v0*ad[2*f] + v1*ad[2*f+1];
    }
    es8[t] = es; ed8[t] = ed;
}

// ---------------- 8-head attention aggregate (thread per node,head), bf16 z ----------------
__global__ void k_attn8(const int* __restrict__ deg, const int* __restrict__ ell,
                        const ushort_t* __restrict__ z8, const float* __restrict__ es8,
                        const float* __restrict__ ed8, const float* __restrict__ bias,
                        ushort_t* __restrict__ out){
    int blk = xswz(blockIdx.x, N_NODES*NHEADS/256);
    int t = blk*blockDim.x + threadIdx.x;
    int n = t >> 3, h = t & 7;
    int dg = deg[n]; if(dg > MAXDEG) dg = MAXDEG;
    float edn = ed8[t];
    float eself = lrelu(es8[t] + edn);
    const int* el = ell + n*MAXDEG;
    float m = eself;
    for(int i=0;i<dg;++i){
        int s = el[i];
        float e = lrelu(es8[s*NHEADS + h] + edn);
        m = fmaxf(m, e);
    }
    float w = expf(eself - m);
    float den = w;
    float acc[F1];
    const uint_t* zn = (const uint_t*)(z8 + (size_t)n*D160 + h*F1);
    #pragma unroll
    for(int f=0; f<10; ++f){
        uint_t v = zn[f];
        acc[2*f]   = w*bf2f((ushort_t)(v & 0xFFFF));
        acc[2*f+1] = w*bf2f((ushort_t)(v >> 16));
    }
    for(int i=0;i<dg;++i){
        int s = el[i];
        float e = lrelu(es8[s*NHEADS + h] + edn);
        float wi = expf(e - m);
        den += wi;
        const uint_t* zs = (const uint_t*)(z8 + (size_t)s*D160 + h*F1);
        #pragma unroll
        for(int f=0; f<10; ++f){
            uint_t v = zs[f];
            acc[2*f]   += wi*bf2f((ushort_t)(v & 0xFFFF));
            acc[2*f+1] += wi*bf2f((ushort_t)(v >> 16));
        }
    }
    float inv = 1.f/(den + 1e-16f);
    uint_t* o = (uint_t*)(out + (size_t)n*D160 + h*F1);
    const float* bb = bias + h*F1;
    #pragma unroll
    for(int f=0; f<10; ++f){
        float v0 = fmaxf(acc[2*f]*inv   + bb[2*f],   0.f);
        float v1 = fmaxf(acc[2*f+1]*inv + bb[2*f+1], 0.f);
        o[f] = (uint_t)f2bf(v0) | ((uint_t)f2bf(v1) << 16);
    }
}

// ---------------- bf16 MFMA GEMM + optional fused row-dot epilogue ----------------
template<int IN, int OUT, bool DOT>
__global__ __launch_bounds__(256) void k_gemm_mfma(const ushort_t* __restrict__ A,
                                                   const float* __restrict__ W,
                                                   ushort_t* __restrict__ C,
                                                   const float* __restrict__ va,
                                                   const float* __restrict__ vb,
                                                   float* __restrict__ oa,
                                                   float* __restrict__ ob){
    constexpr int NT = OUT/16;
    constexpr int KS = IN/32;
    constexpr int LDW = IN + 8;
    __shared__ __align__(16) ushort_t Wt[OUT*LDW];
    int tid = threadIdx.x;
    for(int i = tid; i < IN*OUT; i += 256){
        int k = i / OUT, n = i - k*OUT;
        Wt[n*LDW + k] = f2bf(W[i]);
    }
    __syncthreads();
    int blk = xswz(blockIdx.x, N_NODES/64);
    int wave = tid >> 6, lane = tid & 63;
    int col16 = lane & 15;
    int kq = (lane >> 4) * 8;
    int row = blk*64 + wave*16 + col16;
    const ushort_t* Ar = A + (size_t)row*IN + kq;
    f32x4 acc[NT];
    #pragma unroll
    for(int c=0;c<NT;++c) acc[c] = (f32x4){0.f,0.f,0.f,0.f};
    #pragma unroll
    for(int ks=0; ks<KS; ++ks){
        short8 af = *reinterpret_cast<const short8*>(Ar + ks*32);
        #pragma unroll
        for(int c=0;c<NT;++c){
            short8 bf = *reinterpret_cast<const short8*>(&Wt[(c*16 + col16)*LDW + ks*32 + kq]);
            acc[c] = __builtin_amdgcn_mfma_f32_16x16x32_bf16(af, bf, acc[c], 0, 0, 0);
        }
    }
    int rbase = blk*64 + wave*16 + (lane >> 4)*4;
    #pragma unroll
    for(int c=0;c<NT;++c){
        #pragma unroll
        for(int r=0;r<4;++r){
            C[(size_t)(rbase + r)*OUT + c*16 + col16] = f2bf(acc[c][r]);
        }
    }
    if(DOT){
        float pa[4] = {0,0,0,0}, pb[4] = {0,0,0,0};
        #pragma unroll
        for(int c=0;c<NT;++c){
            float a = va[c*16 + col16];
            float b = vb[c*16 + col16];
            #pragma unroll
            for(int r=0;r<4;++r){ pa[r] += acc[c][r]*a; pb[r] += acc[c][r]*b; }
        }
        #pragma unroll
        for(int o=1;o<16;o<<=1){
            #pragma unroll
            for(int r=0;r<4;++r){ pa[r] += __shfl_xor(pa[r], o); pb[r] += __shfl_xor(pb[r], o); }
        }
        if(col16 == 0){
            #pragma unroll
            for(int r=0;r<4;++r){ oa[rbase + r] = pa[r]; ob[rbase + r] = pb[r]; }
        }
    }
}

// ---------------- 1-head attention aggregate (wave per node), bf16 Z ----------------
// DOT: also compute yrel[n]=h_n . wa, rroot[n]=h_n . wb on the final fp32 h.
template<typename OutT, bool DOT>
__global__ void k_attn1(const int* __restrict__ deg, const int* __restrict__ ell,
                        const ushort_t* __restrict__ Z, const float* __restrict__ es,
                        const float* __restrict__ ed, const float* __restrict__ bias,
                        OutT* __restrict__ out,
                        const float* __restrict__ wa, const float* __restrict__ wb,
                        float* __restrict__ oa, float* __restrict__ ob){
    int blk = xswz(blockIdx.x, N_NODES/4);
    int gt = blk*blockDim.x + threadIdx.x;
    int n = gt >> 6;
    int l = threadIdx.x & 63;
    int dg = deg[n]; if(dg > MAXDEG) dg = MAXDEG;
    float edn = ed[n];
    float eself = lrelu(es[n] + edn);
    int s_l = 0; float e_l = -1e30f;
    if(l < dg){ s_l = ell[n*MAXDEG + l]; e_l = lrelu(es[s_l] + edn); }
    float m = fmaxf(e_l, eself);
    for(int o=32;o>0;o>>=1) m = fmaxf(m, __shfl_xor(m,o));
    float w_l = (l < dg) ? expf(e_l - m) : 0.f;
    float den = w_l;
    for(int o=32;o>0;o>>=1) den += __shfl_xor(den,o);
    float wself = expf(eself - m);
    den += wself;
    float acc0 = wself*bf2f(Z[(size_t)n*HID + l]);
    float acc1 = wself*bf2f(Z[(size_t)n*HID + 64 + l]);
    for(int i=0;i<dg;++i){
        int s = __shfl(s_l, i);
        float w = __shfl(w_l, i);
        acc0 += w*bf2f(Z[(size_t)s*HID + l]);
        acc1 += w*bf2f(Z[(size_t)s*HID + 64 + l]);
    }
    float inv = 1.f/(den + 1e-16f);
    float r0 = fmaxf(acc0*inv + bias[l],      0.f);
    float r1 = fmaxf(acc1*inv + bias[64 + l], 0.f);
    if(sizeof(OutT) == 2){
        ((ushort_t*)out)[(size_t)n*HID + l]      = f2bf(r0);
        ((ushort_t*)out)[(size_t)n*HID + 64 + l] = f2bf(r1);
    } else {
        ((float*)out)[(size_t)n*HID + l]      = r0;
        ((float*)out)[(size_t)n*HID + 64 + l] = r1;
    }
    if(DOT){
        float pa = r0*wa[l] + r1*wa[64+l];
        float pb = r0*wb[l] + r1*wb[64+l];
        for(int o=32;o>0;o>>=1){ pa += __shfl_xor(pa,o); pb += __shfl_xor(pb,o); }
        if(l==0){ oa[n] = pa; ob[n] = pb; }
    }
}

// ---------------- pooling score ----------------
__global__ void k_score(const int* __restrict__ deg, const int* __restrict__ ell,
                        const float* __restrict__ yrel, const float* __restrict__ rroot,
                        const float* __restrict__ bpool, float* __restrict__ score){
    int blk = xswz(blockIdx.x, N_NODES/256);
    int n = blk*blockDim.x + threadIdx.x;
    int dg = deg[n]; if(dg > MAXDEG) dg = MAXDEG;
    float s = rroot[n] + bpool[0];
    const int* el = ell + n*MAXDEG;
    for(int i=0;i<dg;++i) s += yrel[el[i]];
    score[n] = tanhf(s);
}

// ---------------- per-graph top-k: single-wave register bitonic + parallel pool ----------------
__global__ __launch_bounds__(512) void k_topk_pool(const float* __restrict__ score,
                                                   const float* __restrict__ H,
                                                   float* __restrict__ pooled,
                                                   float* __restrict__ perm_f,
                                                   float* __restrict__ sv,
                                                   float* __restrict__ batch_f){
    __shared__ int   sidx[KSEL];
    __shared__ float sval[KSEL];
    __shared__ float pmax[512];
    int g = xswz(blockIdx.x, NGRAPH);
    int base = g*NPG;
    int t = threadIdx.x;
    if(t < 64){
        int l = t;
        u64 v[8];
        #pragma unroll
        for(int r=0;r<8;++r){
            int i = r*64 + l;
            v[r] = comp_make(score[base + i], i);
        }
        // bitonic sort, descending by composite
        #pragma unroll
        for(int kk=1; kk<=9; ++kk){
            int k = 1 << kk;
            #pragma unroll
            for(int jj=kk-1; jj>=0; --jj){
                int j = 1 << jj;
                if(j < 64){
                    bool lower = (l & j) == 0;
                    #pragma unroll
                    for(int r=0;r<8;++r){
                        int i = r*64 + l;
                        u64 p = shfl_xor_u64(v[r], j);
                        bool desc = (i & k) == 0;
                        u64 mx = v[r] > p ? v[r] : p;
                        u64 mn = v[r] > p ? p : v[r];
                        v[r] = (lower == desc) ? mx : mn;
                    }
                } else {
                    int jr = j >> 6;
                    #pragma unroll
                    for(int r=0;r<8;++r){
                        if((r & jr) == 0){
                            int rp = r | jr;
                            int i = r*64 + l;
                            bool desc = (i & k) == 0;
                            u64 a = v[r], b = v[rp];
                            u64 mx = a > b ? a : b;
                            u64 mn = a > b ? b : a;
                            v[r]  = desc ? mx : mn;
                            v[rp] = desc ? mn : mx;
                        }
                    }
                }
            }
        }
        #pragma unroll
        for(int r=0;r<4;++r){
            int i = r*64 + l;
            int idx = comp_idx(v[r]);
            float s = comp_score(v[r]);
            perm_f[g*KSEL + i]  = (float)(base + idx);
            sv[g*KSEL + i]      = s;
            batch_f[g*KSEL + i] = (float)g;
            sidx[i] = idx; sval[i] = s;
        }
    }
    __syncthreads();
    int c = t & 127, kc = t >> 7;
    float mx = -1e30f;
    for(int kk = kc*64; kk < kc*64 + 64; ++kk){
        mx = fmaxf(mx, H[(size_t)(base + sidx[kk])*HID + c] * sval[kk]);
    }
    pmax[t] = mx;
    __syncthreads();
    if(t < HID){
        pooled[g*HID + t] = fmaxf(fmaxf(pmax[t], pmax[t+128]),
                                  fmaxf(pmax[t+256], pmax[t+384]));
    }
}

extern "C" void kernel_launch(void* const* d_in, const int* in_sizes, int n_in,
                              void* d_out, int out_size, void* d_ws, size_t ws_size,
                              hipStream_t stream) {
    const int*   x       = (const int*)  d_in[0];
    const int*   eidx    = (const int*)  d_in[1];
    const float* W_a1    = (const float*)d_in[3];
    const float* asrc_a1 = (const float*)d_in[4];
    const float* adst_a1 = (const float*)d_in[5];
    const float* b_a1    = (const float*)d_in[6];
    const float* W_a2    = (const float*)d_in[7];
    const float* asrc_a2 = (const float*)d_in[8];
    const float* adst_a2 = (const float*)d_in[9];
    const float* b_a2    = (const float*)d_in[10];
    const float* W_b1    = (const float*)d_in[11];
    const float* asrc_b1 = (const float*)d_in[12];
    const float* adst_b1 = (const float*)d_in[13];
    const float* b_b1    = (const float*)d_in[14];
    const float* W_b2    = (const float*)d_in[15];
    const float* asrc_b2 = (const float*)d_in[16];
    const float* adst_b2 = (const float*)d_in[17];
    const float* b_b2    = (const float*)d_in[18];
    const float* w_rel   = (const float*)d_in[19];
    const float* w_root  = (const float*)d_in[20];
    const float* b_pool  = (const float*)d_in[21];

    const int* e_src = eidx;
    const int* e_dst = eidx + E_EDGES;

    char* ws = (char*)d_ws;
    size_t off = 0;
    auto alloc = [&](size_t bytes)->char*{
        char* p = ws + off;
        off += (bytes + 255) & ~(size_t)255;
        return p;
    };
    int*      deg   = (int*)     alloc((size_t)N_NODES*4);
    int*      ell   = (int*)     alloc((size_t)N_NODES*MAXDEG*4);
    ushort_t* z8    = (ushort_t*)alloc((size_t)N_NODES*D160*2);
    ushort_t* h8    = (ushort_t*)alloc((size_t)N_NODES*D160*2);
    ushort_t* zc    = (ushort_t*)alloc((size_t)N_NODES*HID*2);
    ushort_t* hmid  = (ushort_t*)alloc((size_t)N_NODES*HID*2);
    float*    hfin  = (float*)   alloc((size_t)N_NODES*HID*4);
    float*    es8   = (float*)   alloc((size_t)N_NODES*NHEADS*4);
    float*    ed8   = (float*)   alloc((size_t)N_NODES*NHEADS*4);
    float*    es1   = (float*)   alloc((size_t)N_NODES*4);
    float*    ed1   = (float*)   alloc((size_t)N_NODES*4);
    float*    yrel  = (float*)   alloc((size_t)N_NODES*4);
    float*    rroot = (float*)   alloc((size_t)N_NODES*4);
    float*    score = (float*)   alloc((size_t)N_NODES*4);
    (void)ws_size; (void)n_in; (void)in_sizes; (void)out_size;

    float* out      = (float*)d_out;
    float* pooled   = out;
    float* perm_f   = out + NGRAPH*HID;
    float* sv       = perm_f + NGRAPH*KSEL;
    float* batch_f  = sv + NGRAPH*KSEL;

    hipMemsetAsync(deg, 0, (size_t)N_NODES*4, stream);
    k_build_ell<<<E_EDGES/256, 256, 0, stream>>>(e_src, e_dst, deg, ell);

    // ---- GATNet A, conv1 (one-hot gather -> 20x8) ----
    k_a1_z<<<N_NODES*NHEADS/256, 256, 0, stream>>>(x, W_a1, asrc_a1, adst_a1, z8, es8, ed8);
    k_attn8<<<N_NODES*NHEADS/256, 256, 0, stream>>>(deg, ell, z8, es8, ed8, b_a1, h8);

    // ---- GATNet A, conv2 (160 -> 128) + fused es/ed dots ----
    k_gemm_mfma<D160, HID, true><<<N_NODES/64, 256, 0, stream>>>(h8, W_a2, zc, asrc_a2, adst_a2, es1, ed1);
    k_attn1<ushort_t, false><<<N_NODES/4, 256, 0, stream>>>(deg, ell, zc, es1, ed1, b_a2, hmid,
                                                            nullptr, nullptr, nullptr, nullptr);

    // ---- GATNet B, conv1 (128 -> 20x8) ----
    k_gemm_mfma<HID, D160, false><<<N_NODES/64, 256, 0, stream>>>(hmid, W_b1, z8, nullptr, nullptr, nullptr, nullptr);
    k_esed8<<<N_NODES*NHEADS/256, 256, 0, stream>>>(z8, asrc_b1, adst_b1, es8, ed8);
    k_attn8<<<N_NODES*NHEADS/256, 256, 0, stream>>>(deg, ell, z8, es8, ed8, b_b1, h8);

    // ---- GATNet B, conv2 (160 -> 128) + fused es/ed dots ----
    k_gemm_mfma<D160, HID, true><<<N_NODES/64, 256, 0, stream>>>(h8, W_b2, zc, asrc_b2, adst_b2, es1, ed1);
    // final attention + fused pooling dots (yrel, rroot)
    k_attn1<float, true><<<N_NODES/4, 256, 0, stream>>>(deg, ell, zc, es1, ed1, b_b2, hfin,
                                                        w_rel, w_root, yrel, rroot);

    // ---- SAGPooling ----
    k_score<<<N_NODES/256, 256, 0, stream>>>(deg, ell, yrel, rroot, b_pool, score);
    k_topk_pool<<<NGRAPH, NPG, 0, stream>>>(score, hfin, pooled, perm_f, sv, batch_f);
}

// Round 5
// 254.699 us; speedup vs baseline: 3.3612x; 1.0607x over previous
//
#include <hip/hip_runtime.h>
#include <math.h>

#define N_NODES 65536
#define NPG     512
#define NGRAPH  128
#define E_EDGES 524288
#define MAXDEG  64
#define NHEADS  8
#define F1      20
#define HID     128
#define D160    160
#define KSEL    256

typedef unsigned short ushort_t;
typedef unsigned int   uint_t;
typedef unsigned long long u64;
typedef __attribute__((ext_vector_type(8))) short short8;
typedef __attribute__((ext_vector_type(4))) float f32x4;

__device__ __forceinline__ float lrelu(float x){ return x > 0.f ? x : 0.2f*x; }
__device__ __forceinline__ ushort_t f2bf(float f){
    uint_t u = __float_as_uint(f);
    return (ushort_t)((u + 0x7FFFu + ((u >> 16) & 1u)) >> 16);
}
__device__ __forceinline__ float bf2f(ushort_t u){ return __uint_as_float(((uint_t)u) << 16); }
__device__ __forceinline__ float bflo(uint_t v){ return __uint_as_float(v << 16); }
__device__ __forceinline__ float bfhi(uint_t v){ return __uint_as_float(v & 0xFFFF0000u); }
// XCD-coherent block swizzle: graph tiles pinned to one XCD across ALL kernels.
__device__ __forceinline__ int xswz(int bid, int nblocks){
    return (bid & 7) * (nblocks >> 3) + (bid >> 3);
}
__device__ __forceinline__ float rdlanef(float v, int i){
    return __uint_as_float((uint_t)__builtin_amdgcn_readlane(__float_as_int(v), i));
}

// sortable composite: desc score, tie -> asc idx
__device__ __forceinline__ u64 comp_make(float s, int idx){
    uint_t u = __float_as_uint(s);
    u ^= (u & 0x80000000u) ? 0xFFFFFFFFu : 0x80000000u;
    return ((u64)u << 32) | (u64)(511 - idx);
}
__device__ __forceinline__ float comp_score(u64 c){
    uint_t u = (uint_t)(c >> 32);
    u ^= (u & 0x80000000u) ? 0x80000000u : 0xFFFFFFFFu;
    return __uint_as_float(u);
}
__device__ __forceinline__ int comp_idx(u64 c){ return 511 - (int)(c & 0x1FFu); }
__device__ __forceinline__ u64 shfl_xor_u64(u64 x, int m){
    uint_t lo = __shfl_xor((uint_t)x, m);
    uint_t hi = __shfl_xor((uint_t)(x >> 32), m);
    return ((u64)hi << 32) | lo;
}

// ---------------- ELL adjacency build (dst -> list of src) ----------------
__global__ void k_build_ell(const int* __restrict__ src, const int* __restrict__ dst,
                            int* __restrict__ deg, int* __restrict__ ell){
    int blk = xswz(blockIdx.x, E_EDGES/256);
    int e = blk*blockDim.x + threadIdx.x;
    int d = dst[e];
    int p = atomicAdd(&deg[d], 1);
    if(p < MAXDEG) ell[d*MAXDEG + p] = src[e];
}

// ---------------- conv A1: z (bf16) from one-hot gather + es/ed dots ----------------
__global__ void k_a1_z(const int* __restrict__ x, const float* __restrict__ W,
                       const float* __restrict__ asrc, const float* __restrict__ adst,
                       ushort_t* __restrict__ z8, float* __restrict__ es8, float* __restrict__ ed8){
    int blk = xswz(blockIdx.x, N_NODES*NHEADS/256);
    int t = blk*blockDim.x + threadIdx.x;
    int n = t >> 3, h = t & 7;
    int lbl = x[n];
    const float* wrow = W + lbl*D160 + h*F1;
    const float* as = asrc + h*F1;
    const float* ad = adst + h*F1;
    uint_t* zr = (uint_t*)(z8 + (size_t)n*D160 + h*F1);
    float es = 0.f, ed = 0.f;
    #pragma unroll
    for(int f=0; f<10; ++f){
        float v0 = wrow[2*f], v1 = wrow[2*f+1];
        zr[f] = (uint_t)f2bf(v0) | ((uint_t)f2bf(v1) << 16);
        es += v0*as[2*f] + v1*as[2*f+1];
        ed += v0*ad[2*f] + v1*ad[2*f+1];
    }
    es8[t] = es; ed8[t] = ed;
}

// ---------------- es/ed dots for 8-head conv given bf16 z ----------------
__global__ void k_esed8(const ushort_t* __restrict__ z8, const float* __restrict__ asrc,
                        const float* __restrict__ adst,
                        float* __restrict__ es8, float* __restrict__ ed8){
    int blk = xswz(blockIdx.x, N_NODES*NHEADS/256);
    int t = blk*blockDim.x + threadIdx.x;
    int n = t >> 3, h = t & 7;
    const uint_t* zr = (const uint_t*)(z8 + (size_t)n*D160 + h*F1);
    const float* as = asrc + h*F1;
    const float* ad = adst + h*F1;
    float es = 0.f, ed = 0.f;
    #pragma unroll
    for(int f=0; f<10; ++f){
        uint_t v = zr[f];
        float v0 = bflo(v), v1 = bfhi(v);
        es += v0*as[2*f] + v1*as[2*f+1];
        ed += v0*ad[2*f] + v1*ad[2*f+1];
    }
    es8[t] = es; ed8[t] = ed;
}

// ---------------- 8-head attention aggregate (thread per node,head), bf16 z ----------------
__global__ void k_attn8(const int* __restrict__ deg, const int* __restrict__ ell,
                        const ushort_t* __restrict__ z8, const float* __restrict__ es8,
                        const float* __restrict__ ed8, const float* __restrict__ bias,
                        ushort_t* __restrict__ out){
    int blk = xswz(blockIdx.x, N_NODES*NHEADS/256);
    int t = blk*blockDim.x + threadIdx.x;
    int n = t >> 3, h = t & 7;
    int dg = deg[n]; if(dg > MAXDEG) dg = MAXDEG;
    float edn = ed8[t];
    float eself = lrelu(es8[t] + edn);
    const int* el = ell + n*MAXDEG;
    float m = eself;
    {
        int i = 0;
        for(; i+2 <= dg; i += 2){
            int sa = el[i], sb = el[i+1];
            float ea = es8[sa*NHEADS + h], eb = es8[sb*NHEADS + h];
            m = fmaxf(m, fmaxf(lrelu(ea + edn), lrelu(eb + edn)));
        }
        if(i < dg){
            float ea = es8[el[i]*NHEADS + h];
            m = fmaxf(m, lrelu(ea + edn));
        }
    }
    float w = expf(eself - m);
    float den = w;
    float acc[F1];
    const uint_t* zn = (const uint_t*)(z8 + (size_t)n*D160 + h*F1);
    #pragma unroll
    for(int f=0; f<10; ++f){
        uint_t v = zn[f];
        acc[2*f]   = w*bflo(v);
        acc[2*f+1] = w*bfhi(v);
    }
    {
        int i = 0;
        for(; i+2 <= dg; i += 2){
            int sa = el[i], sb = el[i+1];
            float ea = es8[sa*NHEADS + h], eb = es8[sb*NHEADS + h];
            const uint_t* za = (const uint_t*)(z8 + (size_t)sa*D160 + h*F1);
            const uint_t* zb = (const uint_t*)(z8 + (size_t)sb*D160 + h*F1);
            float wa = expf(lrelu(ea + edn) - m);
            float wb = expf(lrelu(eb + edn) - m);
            den += wa + wb;
            #pragma unroll
            for(int f=0; f<10; ++f){
                uint_t va = za[f], vb = zb[f];
                acc[2*f]   += wa*bflo(va) + wb*bflo(vb);
                acc[2*f+1] += wa*bfhi(va) + wb*bfhi(vb);
            }
        }
        if(i < dg){
            int sa = el[i];
            float ea = es8[sa*NHEADS + h];
            const uint_t* za = (const uint_t*)(z8 + (size_t)sa*D160 + h*F1);
            float wa = expf(lrelu(ea + edn) - m);
            den += wa;
            #pragma unroll
            for(int f=0; f<10; ++f){
                uint_t va = za[f];
                acc[2*f]   += wa*bflo(va);
                acc[2*f+1] += wa*bfhi(va);
            }
        }
    }
    float inv = 1.f/(den + 1e-16f);
    uint_t* o = (uint_t*)(out + (size_t)n*D160 + h*F1);
    const float* bb = bias + h*F1;
    #pragma unroll
    for(int f=0; f<10; ++f){
        float v0 = fmaxf(acc[2*f]*inv   + bb[2*f],   0.f);
        float v1 = fmaxf(acc[2*f+1]*inv + bb[2*f+1], 0.f);
        o[f] = (uint_t)f2bf(v0) | ((uint_t)f2bf(v1) << 16);
    }
}

// ---------------- bf16 MFMA GEMM + optional fused row-dot epilogue ----------------
template<int IN, int OUT, bool DOT>
__global__ __launch_bounds__(256) void k_gemm_mfma(const ushort_t* __restrict__ A,
                                                   const float* __restrict__ W,
                                                   ushort_t* __restrict__ C,
                                                   const float* __restrict__ va,
                                                   const float* __restrict__ vb,
                                                   float* __restrict__ oa,
                                                   float* __restrict__ ob){
    constexpr int NT = OUT/16;
    constexpr int KS = IN/32;
    constexpr int LDW = IN + 8;
    __shared__ __align__(16) ushort_t Wt[OUT*LDW];
    int tid = threadIdx.x;
    for(int i = tid; i < IN*OUT; i += 256){
        int k = i / OUT, n = i - k*OUT;
        Wt[n*LDW + k] = f2bf(W[i]);
    }
    __syncthreads();
    int blk = xswz(blockIdx.x, N_NODES/64);
    int wave = tid >> 6, lane = tid & 63;
    int col16 = lane & 15;
    int kq = (lane >> 4) * 8;
    int row = blk*64 + wave*16 + col16;
    const ushort_t* Ar = A + (size_t)row*IN + kq;
    f32x4 acc[NT];
    #pragma unroll
    for(int c=0;c<NT;++c) acc[c] = (f32x4){0.f,0.f,0.f,0.f};
    #pragma unroll
    for(int ks=0; ks<KS; ++ks){
        short8 af = *reinterpret_cast<const short8*>(Ar + ks*32);
        #pragma unroll
        for(int c=0;c<NT;++c){
            short8 bf = *reinterpret_cast<const short8*>(&Wt[(c*16 + col16)*LDW + ks*32 + kq]);
            acc[c] = __builtin_amdgcn_mfma_f32_16x16x32_bf16(af, bf, acc[c], 0, 0, 0);
        }
    }
    int rbase = blk*64 + wave*16 + (lane >> 4)*4;
    #pragma unroll
    for(int c=0;c<NT;++c){
        #pragma unroll
        for(int r=0;r<4;++r){
            C[(size_t)(rbase + r)*OUT + c*16 + col16] = f2bf(acc[c][r]);
        }
    }
    if(DOT){
        float pa[4] = {0,0,0,0}, pb[4] = {0,0,0,0};
        #pragma unroll
        for(int c=0;c<NT;++c){
            float a = va[c*16 + col16];
            float b = vb[c*16 + col16];
            #pragma unroll
            for(int r=0;r<4;++r){ pa[r] += acc[c][r]*a; pb[r] += acc[c][r]*b; }
        }
        #pragma unroll
        for(int o=1;o<16;o<<=1){
            #pragma unroll
            for(int r=0;r<4;++r){ pa[r] += __shfl_xor(pa[r], o); pb[r] += __shfl_xor(pb[r], o); }
        }
        if(col16 == 0){
            #pragma unroll
            for(int r=0;r<4;++r){ oa[rbase + r] = pa[r]; ob[rbase + r] = pb[r]; }
        }
    }
}

// ---------------- 1-head attention aggregate (wave per node), bf16 Z ----------------
// Lane l owns channels (2l, 2l+1): one b32 load per neighbor row.
// Neighbor loop unrolled x4 with readlane broadcasts + batched loads.
template<typename OutT, bool DOT>
__global__ void k_attn1(const int* __restrict__ deg, const int* __restrict__ ell,
                        const ushort_t* __restrict__ Z, const float* __restrict__ es,
                        const float* __restrict__ ed, const float* __restrict__ bias,
                        OutT* __restrict__ out,
                        const float* __restrict__ wa, const float* __restrict__ wb,
                        float* __restrict__ oa, float* __restrict__ ob){
    int blk = xswz(blockIdx.x, N_NODES/4);
    int gt = blk*blockDim.x + threadIdx.x;
    int n = gt >> 6;
    int l = threadIdx.x & 63;
    int dg = deg[n]; if(dg > MAXDEG) dg = MAXDEG;
    float edn = ed[n];
    float eself = lrelu(es[n] + edn);
    int s_l = 0; float e_l = -1e30f;
    if(l < dg){ s_l = ell[n*MAXDEG + l]; e_l = lrelu(es[s_l] + edn); }
    float m = fmaxf(e_l, eself);
    for(int o=32;o>0;o>>=1) m = fmaxf(m, __shfl_xor(m,o));
    float w_l = (l < dg) ? expf(e_l - m) : 0.f;
    float den = w_l;
    for(int o=32;o>0;o>>=1) den += __shfl_xor(den,o);
    float wself = expf(eself - m);
    den += wself;
    const uint_t* Zu = (const uint_t*)Z;
    uint_t zn = Zu[(size_t)n*64 + l];
    float acc0 = wself*bflo(zn);
    float acc1 = wself*bfhi(zn);
    int i = 0;
    for(; i+4 <= dg; i += 4){
        int s0 = __builtin_amdgcn_readlane(s_l, i);
        int s1 = __builtin_amdgcn_readlane(s_l, i+1);
        int s2 = __builtin_amdgcn_readlane(s_l, i+2);
        int s3 = __builtin_amdgcn_readlane(s_l, i+3);
        uint_t z0 = Zu[(size_t)s0*64 + l];
        uint_t z1 = Zu[(size_t)s1*64 + l];
        uint_t z2 = Zu[(size_t)s2*64 + l];
        uint_t z3 = Zu[(size_t)s3*64 + l];
        float w0 = rdlanef(w_l, i);
        float w1 = rdlanef(w_l, i+1);
        float w2 = rdlanef(w_l, i+2);
        float w3 = rdlanef(w_l, i+3);
        acc0 += w0*bflo(z0) + w1*bflo(z1);
        acc1 += w0*bfhi(z0) + w1*bfhi(z1);
        acc0 += w2*bflo(z2) + w3*bflo(z3);
        acc1 += w2*bfhi(z2) + w3*bfhi(z3);
    }
    for(; i < dg; ++i){
        int s0 = __builtin_amdgcn_readlane(s_l, i);
        float w0 = rdlanef(w_l, i);
        uint_t z0 = Zu[(size_t)s0*64 + l];
        acc0 += w0*bflo(z0);
        acc1 += w0*bfhi(z0);
    }
    float inv = 1.f/(den + 1e-16f);
    float2 bb = ((const float2*)bias)[l];
    float r0 = fmaxf(acc0*inv + bb.x, 0.f);
    float r1 = fmaxf(acc1*inv + bb.y, 0.f);
    if(sizeof(OutT) == 2){
        ((uint_t*)out)[(size_t)n*64 + l] = (uint_t)f2bf(r0) | ((uint_t)f2bf(r1) << 16);
    } else {
        float2 rv; rv.x = r0; rv.y = r1;
        ((float2*)out)[(size_t)n*64 + l] = rv;
    }
    if(DOT){
        float2 a2 = ((const float2*)wa)[l];
        float2 b2 = ((const float2*)wb)[l];
        float pa = r0*a2.x + r1*a2.y;
        float pb = r0*b2.x + r1*b2.y;
        for(int o=32;o>0;o>>=1){ pa += __shfl_xor(pa,o); pb += __shfl_xor(pb,o); }
        if(l==0){ oa[n] = pa; ob[n] = pb; }
    }
}

// ---------------- pooling score ----------------
__global__ void k_score(const int* __restrict__ deg, const int* __restrict__ ell,
                        const float* __restrict__ yrel, const float* __restrict__ rroot,
                        const float* __restrict__ bpool, float* __restrict__ score){
    int blk = xswz(blockIdx.x, N_NODES/256);
    int n = blk*blockDim.x + threadIdx.x;
    int dg = deg[n]; if(dg > MAXDEG) dg = MAXDEG;
    float s = rroot[n] + bpool[0];
    const int* el = ell + n*MAXDEG;
    int i = 0;
    for(; i+4 <= dg; i += 4){
        float y0 = yrel[el[i]],   y1 = yrel[el[i+1]];
        float y2 = yrel[el[i+2]], y3 = yrel[el[i+3]];
        s += (y0 + y1) + (y2 + y3);
    }
    for(; i < dg; ++i) s += yrel[el[i]];
    score[n] = tanhf(s);
}

// ---------------- per-graph top-k: single-wave register bitonic + parallel pool ----------------
__global__ __launch_bounds__(512) void k_topk_pool(const float* __restrict__ score,
                                                   const float* __restrict__ H,
                                                   float* __restrict__ pooled,
                                                   float* __restrict__ perm_f,
                                                   float* __restrict__ sv,
                                                   float* __restrict__ batch_f){
    __shared__ int   sidx[KSEL];
    __shared__ float sval[KSEL];
    __shared__ float pmax[512];
    int g = xswz(blockIdx.x, NGRAPH);
    int base = g*NPG;
    int t = threadIdx.x;
    if(t < 64){
        int l = t;
        u64 v[8];
        #pragma unroll
        for(int r=0;r<8;++r){
            int i = r*64 + l;
            v[r] = comp_make(score[base + i], i);
        }
        #pragma unroll
        for(int kk=1; kk<=9; ++kk){
            int k = 1 << kk;
            #pragma unroll
            for(int jj=kk-1; jj>=0; --jj){
                int j = 1 << jj;
                if(j < 64){
                    bool lower = (l & j) == 0;
                    #pragma unroll
                    for(int r=0;r<8;++r){
                        int i = r*64 + l;
                        u64 p = shfl_xor_u64(v[r], j);
                        bool desc = (i & k) == 0;
                        u64 mx = v[r] > p ? v[r] : p;
                        u64 mn = v[r] > p ? p : v[r];
                        v[r] = (lower == desc) ? mx : mn;
                    }
                } else {
                    int jr = j >> 6;
                    #pragma unroll
                    for(int r=0;r<8;++r){
                        if((r & jr) == 0){
                            int rp = r | jr;
                            int i = r*64 + l;
                            bool desc = (i & k) == 0;
                            u64 a = v[r], b = v[rp];
                            u64 mx = a > b ? a : b;
                            u64 mn = a > b ? b : a;
                            v[r]  = desc ? mx : mn;
                            v[rp] = desc ? mn : mx;
                        }
                    }
                }
            }
        }
        #pragma unroll
        for(int r=0;r<4;++r){
            int i = r*64 + l;
            int idx = comp_idx(v[r]);
            float s = comp_score(v[r]);
            perm_f[g*KSEL + i]  = (float)(base + idx);
            sv[g*KSEL + i]      = s;
            batch_f[g*KSEL + i] = (float)g;
            sidx[i] = idx; sval[i] = s;
        }
    }
    __syncthreads();
    int c = t & 127, kc = t >> 7;
    float mx = -1e30f;
    for(int kk = kc*64; kk < kc*64 + 64; ++kk){
        mx = fmaxf(mx, H[(size_t)(base + sidx[kk])*HID + c] * sval[kk]);
    }
    pmax[t] = mx;
    __syncthreads();
    if(t < HID){
        pooled[g*HID + t] = fmaxf(fmaxf(pmax[t], pmax[t+128]),
                                  fmaxf(pmax[t+256], pmax[t+384]));
    }
}

extern "C" void kernel_launch(void* const* d_in, const int* in_sizes, int n_in,
                              void* d_out, int out_size, void* d_ws, size_t ws_size,
                              hipStream_t stream) {
    const int*   x       = (const int*)  d_in[0];
    const int*   eidx    = (const int*)  d_in[1];
    const float* W_a1    = (const float*)d_in[3];
    const float* asrc_a1 = (const float*)d_in[4];
    const float* adst_a1 = (const float*)d_in[5];
    const float* b_a1    = (const float*)d_in[6];
    const float* W_a2    = (const float*)d_in[7];
    const float* asrc_a2 = (const float*)d_in[8];
    const float* adst_a2 = (const float*)d_in[9];
    const float* b_a2    = (const float*)d_in[10];
    const float* W_b1    = (const float*)d_in[11];
    const float* asrc_b1 = (const float*)d_in[12];
    const float* adst_b1 = (const float*)d_in[13];
    const float* b_b1    = (const float*)d_in[14];
    const float* W_b2    = (const float*)d_in[15];
    const float* asrc_b2 = (const float*)d_in[16];
    const float* adst_b2 = (const float*)d_in[17];
    const float* b_b2    = (const float*)d_in[18];
    const float* w_rel   = (const float*)d_in[19];
    const float* w_root  = (const float*)d_in[20];
    const float* b_pool  = (const float*)d_in[21];

    const int* e_src = eidx;
    const int* e_dst = eidx + E_EDGES;

    char* ws = (char*)d_ws;
    size_t off = 0;
    auto alloc = [&](size_t bytes)->char*{
        char* p = ws + off;
        off += (bytes + 255) & ~(size_t)255;
        return p;
    };
    int*      deg   = (int*)     alloc((size_t)N_NODES*4);
    int*      ell   = (int*)     alloc((size_t)N_NODES*MAXDEG*4);
    ushort_t* z8    = (ushort_t*)alloc((size_t)N_NODES*D160*2);
    ushort_t* h8    = (ushort_t*)alloc((size_t)N_NODES*D160*2);
    ushort_t* zc    = (ushort_t*)alloc((size_t)N_NODES*HID*2);
    ushort_t* hmid  = (ushort_t*)alloc((size_t)N_NODES*HID*2);
    float*    hfin  = (float*)   alloc((size_t)N_NODES*HID*4);
    float*    es8   = (float*)   alloc((size_t)N_NODES*NHEADS*4);
    float*    ed8   = (float*)   alloc((size_t)N_NODES*NHEADS*4);
    float*    es1   = (float*)   alloc((size_t)N_NODES*4);
    float*    ed1   = (float*)   alloc((size_t)N_NODES*4);
    float*    yrel  = (float*)   alloc((size_t)N_NODES*4);
    float*    rroot = (float*)   alloc((size_t)N_NODES*4);
    float*    score = (float*)   alloc((size_t)N_NODES*4);
    (void)ws_size; (void)n_in; (void)in_sizes; (void)out_size;

    float* out      = (float*)d_out;
    float* pooled   = out;
    float* perm_f   = out + NGRAPH*HID;
    float* sv       = perm_f + NGRAPH*KSEL;
    float* batch_f  = sv + NGRAPH*KSEL;

    hipMemsetAsync(deg, 0, (size_t)N_NODES*4, stream);
    k_build_ell<<<E_EDGES/256, 256, 0, stream>>>(e_src, e_dst, deg, ell);

    // ---- GATNet A, conv1 (one-hot gather -> 20x8) ----
    k_a1_z<<<N_NODES*NHEADS/256, 256, 0, stream>>>(x, W_a1, asrc_a1, adst_a1, z8, es8, ed8);
    k_attn8<<<N_NODES*NHEADS/256, 256, 0, stream>>>(deg, ell, z8, es8, ed8, b_a1, h8);

    // ---- GATNet A, conv2 (160 -> 128) + fused es/ed dots ----
    k_gemm_mfma<D160, HID, true><<<N_NODES/64, 256, 0, stream>>>(h8, W_a2, zc, asrc_a2, adst_a2, es1, ed1);
    k_attn1<ushort_t, false><<<N_NODES/4, 256, 0, stream>>>(deg, ell, zc, es1, ed1, b_a2, hmid,
                                                            nullptr, nullptr, nullptr, nullptr);

    // ---- GATNet B, conv1 (128 -> 20x8) ----
    k_gemm_mfma<HID, D160, false><<<N_NODES/64, 256, 0, stream>>>(hmid, W_b1, z8, nullptr, nullptr, nullptr, nullptr);
    k_esed8<<<N_NODES*NHEADS/256, 256, 0, stream>>>(z8, asrc_b1, adst_b1, es8, ed8);
    k_attn8<<<N_NODES*NHEADS/256, 256, 0, stream>>>(deg, ell, z8, es8, ed8, b_b1, h8);

    // ---- GATNet B, conv2 (160 -> 128) + fused es/ed dots ----
    k_gemm_mfma<D160, HID, true><<<N_NODES/64, 256, 0, stream>>>(h8, W_b2, zc, asrc_b2, adst_b2, es1, ed1);
    // final attention + fused pooling dots (yrel, rroot)
    k_attn1<float, true><<<N_NODES/4, 256, 0, stream>>>(deg, ell, zc, es1, ed1, b_b2, hfin,
                                                        w_rel, w_root, yrel, rroot);

    // ---- SAGPooling ----
    k_score<<<N_NODES/256, 256, 0, stream>>>(deg, ell, yrel, rroot, b_pool, score);
    k_topk_pool<<<NGRAPH, NPG, 0, stream>>>(score, hfin, pooled, perm_f, sv, batch_f);
}